// Round 16
// baseline (459.440 us; speedup 1.0000x reference)
//
#include <hip/hip_runtime.h>
#include <math.h>

#define B_   2
#define N_   4096
#define S_   48
#define NPL  32
#define NRAYS (B_*N_)          // 8192
#define NPTS  (NRAYS*S_)       // 393216
#define DELTA_ (2.0f/47.0f)

#define ST_ENT   4356                   // 66*66 single-texel entries per plane (8B each)
#define ST_TOTAL (64*ST_ENT)            // 278784
#define PTS_BLK  4096

// ---- workspace layout (float offsets) ----
#define OFF_POSES  0                    // 384
#define OFF_MINMAX 384                  // 2 uints
#define OFF_W1E    512                  // 64*256 bf16
#define OFF_W2E    8704                 // 48*64 bf16
#define OFF_B2E    10240                // 48 floats
#define OFF_ST     16384                // single-texel planes: ST_TOTAL uint2 -> ends 573952
#define OFF_PTS    573952               // float4 per point: NPTS*4 -> ends 2146816
#define OFF_DC     2146816              // depths_c [NPTS]
#define OFF_DF     2540032
#define OFF_SC     2933248
#define OFF_SF     3326464
#define OFF_CC     3719680              // colors_c bf16 [NPTS*32] -> ends 10011136
#define OFF_CF     10011136             // colors_f bf16 -> ends 16302592
#define OFF_FEATS  16302592             // feats: up to NPTS*64 floats (8B/plane-point), chunked

typedef __attribute__((ext_vector_type(8))) short short8;
typedef __attribute__((ext_vector_type(4))) float f32x4;

__device__ __forceinline__ float softplus_f(float x) {
    return fmaxf(x, 0.f) + __logf(1.f + __expf(-fabsf(x)));
}
__device__ __forceinline__ float sigmoid_f(float x) {
    return __builtin_amdgcn_rcpf(1.f + __expf(-x));
}
__device__ __forceinline__ unsigned short bf16rne(float x) {
    unsigned u = __float_as_uint(x);
    u += 0x7FFFu + ((u >> 16) & 1u);
    return (unsigned short)(u >> 16);
}
__device__ __forceinline__ unsigned bf16pk(float lo, float hi) {
    return (unsigned)bf16rne(lo) | ((unsigned)bf16rne(hi) << 16);
}
__device__ __forceinline__ float bf2f(unsigned short v) {
    return __uint_as_float(((unsigned)v) << 16);
}
__device__ __forceinline__ float bflo(unsigned u) { return __uint_as_float(u << 16); }
__device__ __forceinline__ float bfhi(unsigned u) { return __uint_as_float(u & 0xffff0000u); }

__device__ void mul3(const double* a, const double* b, double* o) {
    for (int i = 0; i < 3; i++)
        for (int j = 0; j < 3; j++) {
            double s = 0.0;
            for (int k = 0; k < 3; k++) s += a[i*3+k]*b[k*3+j];
            o[i*3+j] = s;
        }
}

// ---- kernel 0: poses (double math), min/max init, expanded bf16 weights ----
__global__ void k_init(float* ws, const float* __restrict__ W1,
                       const float* __restrict__ W2, const float* __restrict__ b2) {
    int t = threadIdx.x;
    if (t < 32) {
        double y = 1.0 - (t/31.0)*2.0;
        double rr = sqrt(fmax(1.0 - y*y, 0.0));
        double golden = M_PI*(sqrt(5.0) - 1.0);
        double th = golden*(double)t;
        double x = cos(th)*rr, z = sin(th)*rr;
        double phi   = atan2(z, sqrt(x*x + y*y));   // radians treated as degrees (faithful)
        double theta = atan2(y, x);
        double p  = phi/180.0*M_PI;
        double tt = theta/180.0*M_PI;
        double e  = 90.0/180.0*M_PI;
        double cp = cos(p), sp = sin(p), ct = cos(tt), st = sin(tt);
        double ce = cos(e), se = sin(e);
        double Ph[9] = {1,0,0,  0,cp,-sp,  0,sp,cp};
        double Th[9] = {ct,0,-st,  0,1,0,  st,0,ct};
        double Et[9] = {ce,se,0,  -se,ce,0,  0,0,1};
        double M3[9] = {-1,0,0,  0,0,1,  0,1,0};
        double A[9], Bm[9], R[9];
        mul3(Th, Ph, A);
        mul3(Et, A, Bm);
        mul3(M3, Bm, R);
        double radius = -1.307;
        double tv0 = radius*R[2], tv1 = radius*R[5], tv2 = radius*R[8];
        double Rf[9] = {-R[0],R[1],R[2], -R[3],R[4],R[5], -R[6],R[7],R[8]};
        float* P = ws + OFF_POSES + t*12;
        for (int j = 0; j < 3; j++) {
            double r0 = Rf[0*3+j], r1 = Rf[1*3+j], r2 = Rf[2*3+j];
            P[j*4+0] = (float)r0;
            P[j*4+1] = (float)r1;
            P[j*4+2] = (float)r2;
            P[j*4+3] = (float)(-(r0*tv0 + r1*tv1 + r2*tv2));
        }
    }
    if (t == 32) ((unsigned*)(ws + OFF_MINMAX))[0] = 0x7F800000u;
    if (t == 33) ((unsigned*)(ws + OFF_MINMAX))[1] = 0u;
    unsigned short* w1e = (unsigned short*)(ws + OFF_W1E);
    for (int idx = t; idx < 64*256; idx += 256) {
        int n = idx >> 8, k = idx & 255;
        int p = k >> 3, f = k & 7;
        float v = 0.f;
        if (f < 3)      v = W1[(3*p+f)*64 + n];
        else if (f < 5) v = W1[(96 + 2*p + (f-3))*64 + n];
        w1e[idx] = bf16rne(v);
    }
    unsigned short* w2e = (unsigned short*)(ws + OFF_W2E);
    for (int idx = t; idx < 48*64; idx += 256) {
        int n = idx >> 6, k = idx & 63;
        float v = (n < 33) ? W2[k*33 + n] : 0.f;
        w2e[idx] = bf16rne(v);
    }
    for (int idx = t; idx < 48; idx += 256)
        ws[OFF_B2E + idx] = (idx < 33) ? b2[idx] : 0.f;
}

// ---- kernel 1: repack planes to guard-padded bf16 single texels (8B) ----
__global__ __launch_bounds__(256) void k_repack(const float* __restrict__ planes, uint2* __restrict__ st) {
    int idx = blockIdx.x*256 + threadIdx.x;
    if (idx >= ST_TOTAL) return;
    int bp = idx / ST_ENT;
    int rem = idx - bp*ST_ENT;
    int j = rem / 66, i = rem - j*66;
    unsigned ux = 0, uy = 0;
    if (j >= 1 && j <= 64 && i >= 1 && i <= 64) {
        int b = bp >> 5, p = bp & 31;
        const float* src = planes + (((size_t)b*96 + 3*p)*64 + (j-1))*64 + (i-1);
        ux = bf16pk(src[0], src[4096]);
        uy = (unsigned)bf16rne(src[8192]);
    }
    st[idx] = make_uint2(ux, uy);
}

// ---- kernel 1b: point prepass — position+depth once per point ----
__global__ __launch_bounds__(256) void k_pts(
    const float* __restrict__ noise, const float* __restrict__ ro,
    const float* __restrict__ rd, const float* __restrict__ dfin,
    float* __restrict__ dcout, unsigned* __restrict__ mm,
    float4* __restrict__ pts, int coarse)
{
    int pt = blockIdx.x*256 + threadIdx.x;
    if (pt >= NPTS) return;
    int ray = pt / S_;
    float depth;
    if (coarse) {
        int j = pt - ray*S_;
        depth = 0.5f + (float)j*DELTA_ + noise[pt]*DELTA_;
        dcout[pt] = depth;
        float mn = depth, mx = depth;
        for (int off = 32; off > 0; off >>= 1) {
            mn = fminf(mn, __shfl_down(mn, off));
            mx = fmaxf(mx, __shfl_down(mx, off));
        }
        if ((threadIdx.x & 63) == 0) {
            atomicMin(mm + 0, __float_as_uint(mn));
            atomicMax(mm + 1, __float_as_uint(mx));
        }
    } else depth = dfin[pt];
    float px = fmaf(depth, rd[ray*3+0], ro[ray*3+0]);
    float py = fmaf(depth, rd[ray*3+1], ro[ray*3+1]);
    float pz = fmaf(depth, rd[ray*3+2], ro[ray*3+2]);
    pts[pt] = make_float4(px, py, pz, depth);
}

// ---- kernel 2a: LDS-staged gather (block = one plane x 4096-point range) ----
// inner iteration: ONE 16B pts load + 2 LDS taps + interp + 8B store
__global__ __launch_bounds__(256) void k_gather(
    const uint2* __restrict__ st, const float4* __restrict__ pts,
    const float* __restrict__ poses,
    unsigned short* __restrict__ feats, int base_pt, int chunk_pts)
{
    __shared__ uint2 tex[ST_ENT];       // 34848 B
    int tid = threadIdx.x;
    int p  = blockIdx.x & 31;           // plane
    int pr = blockIdx.x >> 5;           // point-range index within chunk
    int r0 = pr*PTS_BLK;
    int b = (base_pt + r0 >= NPTS/2) ? 1 : 0;   // PTS_BLK divides NPTS/2
    const uint2* src = st + (size_t)(b*32 + p)*ST_ENT;
    for (int i = tid; i < ST_ENT; i += 256) tex[i] = src[i];
    const float* P = poses + p*12;
    float P0 = P[0], P1 = P[1], P2 = P[2],  P3 = P[3];
    float P4 = P[4], P5 = P[5], P6 = P[6],  P7 = P[7];
    float P8 = P[8], P9 = P[9], P10 = P[10], P11 = P[11];
    __syncthreads();

    for (int it = 0; it < PTS_BLK/256; it++) {
        int ptl = r0 + it*256 + tid;
        float4 pv = pts[base_pt + ptl];
        float px = pv.x, py = pv.y, pz = pv.z;
        float c0 = fmaf(P0,px, fmaf(P1,py, fmaf(P2,pz, P3)));
        float c1 = fmaf(P4,px, fmaf(P5,py, fmaf(P6,pz, P7)));
        float c2 = fmaf(P8,px, fmaf(P9,py, fmaf(P10,pz, P11)));
        float rz = __builtin_amdgcn_rcpf(c2);
        float gx = fminf(fmaxf((1.0254f*c0 + 0.5f*c2)*rz, 0.f), 1.f)*2.f - 1.f;
        float gy = fminf(fmaxf((1.0254f*c1 + 0.5f*c2)*rz, 0.f), 1.f)*2.f - 1.f;
        float ixp = ((gx + 1.f)*64.f - 1.f)*0.5f + 1.f;
        float iyp = ((gy + 1.f)*64.f - 1.f)*0.5f + 1.f;
        float xf = floorf(ixp), yf = floorf(iyp);
        float wx = ixp - xf, wy = iyp - yf;
        int x0p = (int)xf, y0p = (int)yf;     // [0,64]
        const uint2* e = tex + y0p*66 + x0p;
        uint2 e00 = e[0], e01 = e[1], e10 = e[66], e11 = e[67];
        float wy0 = 1.f - wy, wy1 = wy;
        float w0x = 1.f - wx, w1x = wx;
        float tl0 = fmaf(wy0, bflo(e00.x), wy1*bflo(e10.x));
        float tl1 = fmaf(wy0, bfhi(e00.x), wy1*bfhi(e10.x));
        float tl2 = fmaf(wy0, bflo(e00.y), wy1*bflo(e10.y));
        float tr0 = fmaf(wy0, bflo(e01.x), wy1*bflo(e11.x));
        float tr1 = fmaf(wy0, bfhi(e01.x), wy1*bfhi(e11.x));
        float tr2 = fmaf(wy0, bflo(e01.y), wy1*bflo(e11.y));
        float f0 = fmaf(w0x, tl0, w1x*tr0);
        float f1 = fmaf(w0x, tl1, w1x*tr1);
        float f2 = fmaf(w0x, tl2, w1x*tr2);
        uint2 av;
        av.x = bf16pk(f0, f1);
        av.y = (unsigned)bf16rne(f2);
        *(uint2*)(feats + ((size_t)p*chunk_pts + ptl)*4) = av;   // 8B/plane-point
    }
}

// ---- kernel 2b: MFMA MLP; gx,gy recomputed from pts (feats carries f0,f1,f2) ----
__global__ __launch_bounds__(256) void k_mlp(
    const unsigned short* __restrict__ feats, const float4* __restrict__ pts,
    const float* __restrict__ poses,
    const float* __restrict__ b1, const unsigned short* __restrict__ w1e,
    const unsigned short* __restrict__ w2e, const float* __restrict__ b2e,
    unsigned short* __restrict__ colors, float* __restrict__ dens,
    int base_pt, int chunk_pts)
{
    __shared__ __align__(16) unsigned short smem[4][4608];
    __shared__ float pls[384];
    int tid = threadIdx.x;
    int wv = tid >> 6, lane = tid & 63;
    int n = lane & 15, q = lane >> 4;
    int wlocal = blockIdx.x*256 + wv*64;
    for (int i = tid; i < 384; i += 256) pls[i] = poses[i];
    __syncthreads();

    float px[4], py[4], pz[4];
#pragma unroll
    for (int t = 0; t < 4; t++) {
        float4 pv = pts[base_pt + wlocal + t*16 + n];
        px[t] = pv.x; py[t] = pv.y; pz[t] = pv.z;
    }

    f32x4 acc[4][4];
#pragma unroll
    for (int t = 0; t < 4; t++)
#pragma unroll
        for (int nt = 0; nt < 4; nt++) {
            float bv = b1[nt*16 + n];
            acc[t][nt] = (f32x4){bv, bv, bv, bv};
        }

    for (int s = 0; s < 8; s++) {
        short8 bf[4];
#pragma unroll
        for (int nt = 0; nt < 4; nt++)
            bf[nt] = *(const short8*)(w1e + (nt*16 + n)*256 + s*32 + q*8);
        int plane = s*4 + q;
        const float* P = pls + plane*12;
#pragma unroll
        for (int t = 0; t < 4; t++) {
            uint2 fv = *(const uint2*)(feats + ((size_t)plane*chunk_pts + wlocal + t*16 + n)*4);
            float c0 = fmaf(P[0],px[t], fmaf(P[1],py[t], fmaf(P[2],pz[t], P[3])));
            float c1 = fmaf(P[4],px[t], fmaf(P[5],py[t], fmaf(P[6],pz[t], P[7])));
            float c2 = fmaf(P[8],px[t], fmaf(P[9],py[t], fmaf(P[10],pz[t], P[11])));
            float rz = __builtin_amdgcn_rcpf(c2);
            float gx = fminf(fmaxf((1.0254f*c0 + 0.5f*c2)*rz, 0.f), 1.f)*2.f - 1.f;
            float gy = fminf(fmaxf((1.0254f*c1 + 0.5f*c2)*rz, 0.f), 1.f)*2.f - 1.f;
            union { short8 s8; uint4 u; } av;
            av.u.x = fv.x;                                              // f0,f1
            av.u.y = (fv.y & 0xffffu) | ((unsigned)bf16rne(gx) << 16);  // f2,gx
            av.u.z = (unsigned)bf16rne(gy);                             // gy,0
            av.u.w = 0u;
#pragma unroll
            for (int nt = 0; nt < 4; nt++)
                acc[t][nt] = __builtin_amdgcn_mfma_f32_16x16x32_bf16(av.s8, bf[nt], acc[t][nt], 0, 0, 0);
        }
    }

    unsigned short* ht = &smem[wv][0];
#pragma unroll
    for (int t = 0; t < 4; t++)
#pragma unroll
        for (int nt = 0; nt < 4; nt++)
#pragma unroll
            for (int r = 0; r < 4; r++) {
                float hv = softplus_f(acc[t][nt][r]);
                ht[(t*16 + q*4 + r)*72 + nt*16 + n] = bf16rne(hv);
            }
    short8 a2[4][2];
#pragma unroll
    for (int t = 0; t < 4; t++)
#pragma unroll
        for (int s2 = 0; s2 < 2; s2++)
            a2[t][s2] = *(const short8*)(ht + (t*16 + n)*72 + s2*32 + q*8);
    // no __syncthreads: aliasing is wave-local; DS pipe in-order per wave

    f32x4 acc2[4][3];
#pragma unroll
    for (int t = 0; t < 4; t++)
#pragma unroll
        for (int nt = 0; nt < 3; nt++) {
            float bv = b2e[nt*16 + n];
            acc2[t][nt] = (f32x4){bv, bv, bv, bv};
        }
    short8 b2f[3][2];
#pragma unroll
    for (int nt = 0; nt < 3; nt++)
#pragma unroll
        for (int s2 = 0; s2 < 2; s2++)
            b2f[nt][s2] = *(const short8*)(w2e + (nt*16 + n)*64 + s2*32 + q*8);
#pragma unroll
    for (int t = 0; t < 4; t++)
#pragma unroll
        for (int nt = 0; nt < 3; nt++)
#pragma unroll
            for (int s2 = 0; s2 < 2; s2++)
                acc2[t][nt] = __builtin_amdgcn_mfma_f32_16x16x32_bf16(a2[t][s2], b2f[nt][s2], acc2[t][nt], 0, 0, 0);

    float* ot = (float*)&smem[wv][0];
#pragma unroll
    for (int t = 0; t < 4; t++)
#pragma unroll
        for (int nt = 0; nt < 3; nt++) {
            int col = nt*16 + n;
#pragma unroll
            for (int r = 0; r < 4; r++) {
                float v = acc2[t][nt][r];
                int row = t*16 + q*4 + r;
                if (col == 0) ot[row*34 + 32] = v;
                else if (col <= 32) {
                    float sg = sigmoid_f(v);
                    ot[row*34 + (col-1)] = fmaf(sg, 1.002f, -0.001f);
                }
            }
        }
    unsigned* cgu = (unsigned*)(colors + (size_t)(base_pt + wlocal)*32);
    for (int i = 0; i < 16; i++) {
        int ui = i*64 + lane;
        int pt = ui >> 4, ch = (ui & 15)*2;
        cgu[ui] = bf16pk(ot[pt*34 + ch], ot[pt*34 + ch + 1]);
    }
    dens[base_pt + wlocal + lane] = ot[lane*34 + 32];
}

// ---- kernel 3: coarse march + pdf + importance samples (wave per ray) ----
__global__ __launch_bounds__(256) void k_imp(const float* __restrict__ u, float* ws) {
    __shared__ float zl[4][48];
    __shared__ float cdfl[4][46];
    int tid = threadIdx.x;
    int wv = tid >> 6, lane = tid & 63;
    int r = blockIdx.x*4 + wv;
    const float* z   = ws + OFF_DC + (size_t)r*48;
    const float* den = ws + OFF_SC + (size_t)r*48;
    float zv = 0.f, dv = 0.f;
    if (lane < 48) { zv = z[lane]; dv = den[lane]; zl[wv][lane] = zv; }
    float zn  = __shfl_down(zv, 1);
    float dnn = __shfl_down(dv, 1);
    float alpha = 0.f, f = 1.f;
    if (lane < 47) {
        float sp = softplus_f(0.5f*(dv + dnn) - 1.f);
        alpha = 1.f - __expf(-sp*(zn - zv));
        f = 1.f - alpha + 1e-10f;
    }
    float v = f;
    for (int off = 1; off < 64; off <<= 1) { float o = __shfl_up(v, off); if (lane >= off) v *= o; }
    float T = __shfl_up(v, 1); if (lane == 0) T = 1.f;
    float w = alpha*T;
    float wn1 = __shfl_down(w, 1), wn2 = __shfl_down(w, 2);
    float pw = 0.f;
    if (lane < 45) pw = 0.5f*(fmaxf(w, wn1) + fmaxf(wn1, wn2)) + 0.01f + 1e-5f;
    float s = pw;
    for (int off = 1; off < 64; off <<= 1) { float o = __shfl_up(s, off); if (lane >= off) s += o; }
    float csum = __shfl(s, 63);
    if (lane < 45) cdfl[wv][lane+1] = s/csum;
    if (lane == 63) cdfl[wv][0] = 0.f;
    __syncthreads();
    if (lane < 48) {
        float uu = u[(size_t)r*48 + lane];
        int lo = 0, hi = 46;
        while (lo < hi) { int mid = (lo+hi)>>1; if (uu >= cdfl[wv][mid]) lo = mid+1; else hi = mid; }
        int below = max(lo-1, 0), above = min(lo, 45);
        float cb = cdfl[wv][below], ca = cdfl[wv][above];
        float zb = zl[wv][below],   za = zl[wv][above];
        float dn2 = ca - cb; if (dn2 < 1e-5f) dn2 = 1.f;
        ws[OFF_DF + (size_t)r*48 + lane] = zb + (uu - cb)/dn2*(za - zb);
    }
}

// ---- kernel 5: fused sort + march + color accumulation (wave per ray) ----
__global__ __launch_bounds__(256) void k_final(float* __restrict__ out, const float* __restrict__ ws,
                                               const unsigned short* __restrict__ cC,
                                               const unsigned short* __restrict__ cF)
{
    __shared__ float kd[4][96];
    __shared__ float kden[4][96];
    __shared__ float sdl[4][96];
    __shared__ float sdenl[4][96];
    __shared__ int   sidxl[4][96];
    __shared__ float warr[4][96];
    __shared__ float earr[4][96];
    int tid = threadIdx.x;
    int wv = tid >> 6, lane = tid & 63;
    int r = blockIdx.x*4 + wv;
    const float* dc = ws + OFF_DC + (size_t)r*48;
    const float* df = ws + OFF_DF + (size_t)r*48;
    const float* sc = ws + OFF_SC + (size_t)r*48;
    const float* sf = ws + OFF_SF + (size_t)r*48;
    for (int i = lane; i < 96; i += 64) {
        float d, dn;
        if (i < 48) { d = dc[i]; dn = sc[i]; }
        else        { d = df[i-48]; dn = sf[i-48]; }
        kd[wv][i] = d; kden[wv][i] = dn;
    }
    __syncthreads();
    for (int i = lane; i < 96; i += 64) {
        float d = kd[wv][i];
        int rank = 0;
        for (int j = 0; j < 96; j++) {
            float dj = kd[wv][j];
            rank += (int)((dj < d) | ((dj == d) & (j < i)));
        }
        sdl[wv][rank] = d; sdenl[wv][rank] = kden[wv][i]; sidxl[wv][rank] = i;
    }
    __syncthreads();
    int i2 = 2*lane;
    float a0=0.f, f0=1.f, a1=0.f, f1=1.f, d0=0.f, d1=0.f, d2=0.f;
    if (i2 < 95) {
        d0 = sdl[wv][i2]; d1 = sdl[wv][i2+1];
        float sp = softplus_f(0.5f*(sdenl[wv][i2] + sdenl[wv][i2+1]) - 1.f);
        a0 = 1.f - __expf(-sp*(d1 - d0)); f0 = 1.f - a0 + 1e-10f;
    }
    if (i2+1 < 95) {
        d2 = sdl[wv][i2+2];
        float sp = softplus_f(0.5f*(sdenl[wv][i2+1] + sdenl[wv][i2+2]) - 1.f);
        a1 = 1.f - __expf(-sp*(d2 - d1)); f1 = 1.f - a1 + 1e-10f;
    }
    float p = f0*f1, v = p;
    for (int off = 1; off < 64; off <<= 1) { float o = __shfl_up(v, off); if (lane >= off) v *= o; }
    float excl = __shfl_up(v, 1); if (lane == 0) excl = 1.f;
    float w0 = a0*excl, w1 = a1*excl*f0;
    if (i2   < 96) warr[wv][i2]   = w0;
    if (i2+1 < 96) warr[wv][i2+1] = w1;
    float wsm = w0 + w1;
    float dsm = w0*0.5f*(d0+d1) + w1*0.5f*(d1+d2);
    for (int off = 32; off; off >>= 1) { wsm += __shfl_xor(wsm, off); dsm += __shfl_xor(dsm, off); }
    __syncthreads();
    for (int i = lane; i < 96; i += 64) {
        float wp = (i > 0)  ? warr[wv][i-1] : 0.f;
        float wc = (i < 95) ? warr[wv][i]   : 0.f;
        earr[wv][sidxl[wv][i]] = 0.5f*(wp + wc);
    }
    __syncthreads();
    int ch = lane & 31, half = lane >> 5;
    const unsigned short* cbase = (half ? cF : cC) + ((size_t)r*48)*32 + ch;
    const float* eb = &earr[wv][half*48];
    float a = 0.f;
    for (int jj = 0; jj < 48; jj++)
        a = fmaf(eb[jj], bf2f(cbase[(size_t)jj*32]), a);
    a += __shfl_xor(a, 32);
    if (lane < 32) out[(size_t)r*34 + lane] = 2.f*a - 1.f;
    if (lane == 0) {
        float gmn = __uint_as_float(((const unsigned*)(ws + OFF_MINMAX))[0]);
        float gmx = __uint_as_float(((const unsigned*)(ws + OFF_MINMAX))[1]);
        float depth = dsm/wsm;
        if (depth != depth) depth = __builtin_inff();
        depth = fminf(fmaxf(depth, gmn), gmx);
        out[(size_t)r*34 + 32] = depth;
        out[(size_t)r*34 + 33] = wsm;
    }
}

extern "C" void kernel_launch(void* const* d_in, const int* in_sizes, int n_in,
                              void* d_out, int out_size, void* d_ws, size_t ws_size,
                              hipStream_t stream) {
    const float* planes = (const float*)d_in[0];
    const float* ro     = (const float*)d_in[1];
    const float* rd     = (const float*)d_in[2];
    const float* noise  = (const float*)d_in[3];
    const float* u      = (const float*)d_in[4];
    const float* W1     = (const float*)d_in[5];
    const float* b1     = (const float*)d_in[6];
    const float* W2     = (const float*)d_in[7];
    const float* b2     = (const float*)d_in[8];
    float* ws  = (float*)d_ws;
    float* out = (float*)d_out;
    const unsigned short* w1e = (const unsigned short*)(ws + OFF_W1E);
    const unsigned short* w2e = (const unsigned short*)(ws + OFF_W2E);
    uint2* st = (uint2*)(ws + OFF_ST);
    float4* pts = (float4*)(ws + OFF_PTS);
    unsigned short* cC = (unsigned short*)(ws + OFF_CC);
    unsigned short* cF = (unsigned short*)(ws + OFF_CF);
    unsigned short* feats = (unsigned short*)(ws + OFF_FEATS);
    unsigned* mm = (unsigned*)(ws + OFF_MINMAX);

    // chunk the feats buffer (64 floats/point) to whatever ws_size allows
    long cap = (long)(ws_size/sizeof(float)) - OFF_FEATS;
    int chunk = NPTS;
    while ((long)chunk*64 > cap && chunk > 3*PTS_BLK) chunk >>= 1;
    int nch = NPTS/chunk;

    hipLaunchKernelGGL(k_init,   dim3(1),    dim3(256), 0, stream, ws, W1, W2, b2);
    hipLaunchKernelGGL(k_repack, dim3((ST_TOTAL + 255)/256), dim3(256), 0, stream, planes, st);
    hipLaunchKernelGGL(k_pts,    dim3(NPTS/256), dim3(256), 0, stream,
                       noise, ro, rd, (const float*)nullptr, ws + OFF_DC, mm, pts, 1);
    for (int c = 0; c < nch; c++) {
        hipLaunchKernelGGL(k_gather, dim3((chunk/PTS_BLK)*32), dim3(256), 0, stream,
                           st, pts, ws + OFF_POSES, feats, c*chunk, chunk);
        hipLaunchKernelGGL(k_mlp,    dim3(chunk/256), dim3(256), 0, stream,
                           feats, pts, ws + OFF_POSES,
                           b1, w1e, w2e, ws + OFF_B2E, cC, ws + OFF_SC, c*chunk, chunk);
    }
    hipLaunchKernelGGL(k_imp, dim3(NRAYS/4), dim3(256), 0, stream, u, ws);
    hipLaunchKernelGGL(k_pts, dim3(NPTS/256), dim3(256), 0, stream,
                       noise, ro, rd, ws + OFF_DF, ws + OFF_DC, mm, pts, 0);
    for (int c = 0; c < nch; c++) {
        hipLaunchKernelGGL(k_gather, dim3((chunk/PTS_BLK)*32), dim3(256), 0, stream,
                           st, pts, ws + OFF_POSES, feats, c*chunk, chunk);
        hipLaunchKernelGGL(k_mlp,    dim3(chunk/256), dim3(256), 0, stream,
                           feats, pts, ws + OFF_POSES,
                           b1, w1e, w2e, ws + OFF_B2E, cF, ws + OFF_SF, c*chunk, chunk);
    }
    hipLaunchKernelGGL(k_final, dim3(NRAYS/4), dim3(256), 0, stream, out, ws, cC, cF);
}

// Round 17
// 333.525 us; speedup vs baseline: 1.3775x; 1.3775x over previous
//
#include <hip/hip_runtime.h>
#include <math.h>

#define B_   2
#define N_   4096
#define S_   48
#define NPL  32
#define NRAYS (B_*N_)          // 8192
#define NPTS  (NRAYS*S_)       // 393216
#define DELTA_ (2.0f/47.0f)

#define ST_ENT   4356                   // 66*66 single-texel entries per plane (8B each)
#define ST_TOTAL (64*ST_ENT)            // 278784
#define PTS_BLK  4096

// ---- workspace layout (float offsets) ----
#define OFF_POSES  0                    // 384
#define OFF_MINMAX 384                  // 2 floats (gmin, gmax)
#define OFF_W1E    512                  // 64*256 bf16
#define OFF_W2E    8704                 // 48*64 bf16
#define OFF_B2E    10240                // 48 floats
#define OFF_ST     16384                // single-texel planes: ST_TOTAL uint2 -> ends 573952
#define OFF_PTS    573952               // float4 per point: NPTS*4 -> ends 2146816
#define OFF_DC     2146816              // depths_c [NPTS]
#define OFF_DF     2540032
#define OFF_SC     2933248
#define OFF_SF     3326464
#define OFF_CC     3719680              // colors_c bf16 [NPTS*32] -> ends 10011136
#define OFF_CF     10011136             // colors_f bf16 -> ends 16302592
#define OFF_FEATS  16302592             // feats: up to NPTS*64 floats (8B/plane-point), chunked

typedef __attribute__((ext_vector_type(8))) short short8;
typedef __attribute__((ext_vector_type(4))) float f32x4;

__device__ __forceinline__ float softplus_f(float x) {
    return fmaxf(x, 0.f) + __logf(1.f + __expf(-fabsf(x)));
}
__device__ __forceinline__ float sigmoid_f(float x) {
    return __builtin_amdgcn_rcpf(1.f + __expf(-x));
}
__device__ __forceinline__ unsigned short bf16rne(float x) {
    unsigned u = __float_as_uint(x);
    u += 0x7FFFu + ((u >> 16) & 1u);
    return (unsigned short)(u >> 16);
}
__device__ __forceinline__ unsigned bf16pk(float lo, float hi) {
    return (unsigned)bf16rne(lo) | ((unsigned)bf16rne(hi) << 16);
}
__device__ __forceinline__ float bf2f(unsigned short v) {
    return __uint_as_float(((unsigned)v) << 16);
}
__device__ __forceinline__ float bflo(unsigned u) { return __uint_as_float(u << 16); }
__device__ __forceinline__ float bfhi(unsigned u) { return __uint_as_float(u & 0xffff0000u); }

__device__ void mul3(const double* a, const double* b, double* o) {
    for (int i = 0; i < 3; i++)
        for (int j = 0; j < 3; j++) {
            double s = 0.0;
            for (int k = 0; k < 3; k++) s += a[i*3+k]*b[k*3+j];
            o[i*3+j] = s;
        }
}

// ---- kernel 0: poses (double math), minmax reduction (no atomics), bf16 weights ----
// global depth-clip bounds: noise in [0,1) => min only from sample j=0, max only from j=47
__global__ void k_init(float* ws, const float* __restrict__ W1,
                       const float* __restrict__ W2, const float* __restrict__ b2,
                       const float* __restrict__ noise) {
    __shared__ float redmn[4], redmx[4];
    int t = threadIdx.x;
    if (t < 32) {
        double y = 1.0 - (t/31.0)*2.0;
        double rr = sqrt(fmax(1.0 - y*y, 0.0));
        double golden = M_PI*(sqrt(5.0) - 1.0);
        double th = golden*(double)t;
        double x = cos(th)*rr, z = sin(th)*rr;
        double phi   = atan2(z, sqrt(x*x + y*y));   // radians treated as degrees (faithful)
        double theta = atan2(y, x);
        double p  = phi/180.0*M_PI;
        double tt = theta/180.0*M_PI;
        double e  = 90.0/180.0*M_PI;
        double cp = cos(p), sp = sin(p), ct = cos(tt), st = sin(tt);
        double ce = cos(e), se = sin(e);
        double Ph[9] = {1,0,0,  0,cp,-sp,  0,sp,cp};
        double Th[9] = {ct,0,-st,  0,1,0,  st,0,ct};
        double Et[9] = {ce,se,0,  -se,ce,0,  0,0,1};
        double M3[9] = {-1,0,0,  0,0,1,  0,1,0};
        double A[9], Bm[9], R[9];
        mul3(Th, Ph, A);
        mul3(Et, A, Bm);
        mul3(M3, Bm, R);
        double radius = -1.307;
        double tv0 = radius*R[2], tv1 = radius*R[5], tv2 = radius*R[8];
        double Rf[9] = {-R[0],R[1],R[2], -R[3],R[4],R[5], -R[6],R[7],R[8]};
        float* P = ws + OFF_POSES + t*12;
        for (int j = 0; j < 3; j++) {
            double r0 = Rf[0*3+j], r1 = Rf[1*3+j], r2 = Rf[2*3+j];
            P[j*4+0] = (float)r0;
            P[j*4+1] = (float)r1;
            P[j*4+2] = (float)r2;
            P[j*4+3] = (float)(-(r0*tv0 + r1*tv1 + r2*tv2));
        }
    }
    unsigned short* w1e = (unsigned short*)(ws + OFF_W1E);
    for (int idx = t; idx < 64*256; idx += 256) {
        int n = idx >> 8, k = idx & 255;
        int p = k >> 3, f = k & 7;
        float v = 0.f;
        if (f < 3)      v = W1[(3*p+f)*64 + n];
        else if (f < 5) v = W1[(96 + 2*p + (f-3))*64 + n];
        w1e[idx] = bf16rne(v);
    }
    unsigned short* w2e = (unsigned short*)(ws + OFF_W2E);
    for (int idx = t; idx < 48*64; idx += 256) {
        int n = idx >> 6, k = idx & 63;
        float v = (n < 33) ? W2[k*33 + n] : 0.f;
        w2e[idx] = bf16rne(v);
    }
    for (int idx = t; idx < 48; idx += 256)
        ws[OFF_B2E + idx] = (idx < 33) ? b2[idx] : 0.f;

    // minmax over noise col 0 / col 47 (one block, no atomics)
    float mn = 1e30f, mx = -1e30f;
    for (int r = t; r < NRAYS; r += 256) {
        float n0  = noise[(size_t)r*48];
        float n47 = noise[(size_t)r*48 + 47];
        mn = fminf(mn, 0.5f + n0*DELTA_);
        mx = fmaxf(mx, 0.5f + 47.f*DELTA_ + n47*DELTA_);
    }
    for (int off = 32; off > 0; off >>= 1) {
        mn = fminf(mn, __shfl_down(mn, off));
        mx = fmaxf(mx, __shfl_down(mx, off));
    }
    if ((t & 63) == 0) { redmn[t >> 6] = mn; redmx[t >> 6] = mx; }
    __syncthreads();
    if (t == 0) {
        ws[OFF_MINMAX]     = fminf(fminf(redmn[0], redmn[1]), fminf(redmn[2], redmn[3]));
        ws[OFF_MINMAX + 1] = fmaxf(fmaxf(redmx[0], redmx[1]), fmaxf(redmx[2], redmx[3]));
    }
}

// ---- kernel 1: repack planes to guard-padded bf16 single texels (8B) ----
__global__ __launch_bounds__(256) void k_repack(const float* __restrict__ planes, uint2* __restrict__ st) {
    int idx = blockIdx.x*256 + threadIdx.x;
    if (idx >= ST_TOTAL) return;
    int bp = idx / ST_ENT;
    int rem = idx - bp*ST_ENT;
    int j = rem / 66, i = rem - j*66;
    unsigned ux = 0, uy = 0;
    if (j >= 1 && j <= 64 && i >= 1 && i <= 64) {
        int b = bp >> 5, p = bp & 31;
        const float* src = planes + (((size_t)b*96 + 3*p)*64 + (j-1))*64 + (i-1);
        ux = bf16pk(src[0], src[4096]);
        uy = (unsigned)bf16rne(src[8192]);
    }
    st[idx] = make_uint2(ux, uy);
}

// ---- kernel 1b: point prepass — position+depth once per point (no atomics) ----
__global__ __launch_bounds__(256) void k_pts(
    const float* __restrict__ noise, const float* __restrict__ ro,
    const float* __restrict__ rd, const float* __restrict__ dfin,
    float* __restrict__ dcout, float4* __restrict__ pts, int coarse)
{
    int pt = blockIdx.x*256 + threadIdx.x;
    if (pt >= NPTS) return;
    int ray = pt / S_;
    float depth;
    if (coarse) {
        int j = pt - ray*S_;
        depth = 0.5f + (float)j*DELTA_ + noise[pt]*DELTA_;
        dcout[pt] = depth;
    } else depth = dfin[pt];
    float px = fmaf(depth, rd[ray*3+0], ro[ray*3+0]);
    float py = fmaf(depth, rd[ray*3+1], ro[ray*3+1]);
    float pz = fmaf(depth, rd[ray*3+2], ro[ray*3+2]);
    pts[pt] = make_float4(px, py, pz, depth);
}

// ---- kernel 2a: LDS-staged gather (block = one plane x 4096-point range) ----
__global__ __launch_bounds__(256) void k_gather(
    const uint2* __restrict__ st, const float4* __restrict__ pts,
    const float* __restrict__ poses,
    unsigned short* __restrict__ feats, int base_pt, int chunk_pts)
{
    __shared__ uint2 tex[ST_ENT];       // 34848 B
    int tid = threadIdx.x;
    int p  = blockIdx.x & 31;           // plane
    int pr = blockIdx.x >> 5;           // point-range index within chunk
    int r0 = pr*PTS_BLK;
    int b = (base_pt + r0 >= NPTS/2) ? 1 : 0;   // PTS_BLK divides NPTS/2
    const uint2* src = st + (size_t)(b*32 + p)*ST_ENT;
    for (int i = tid; i < ST_ENT; i += 256) tex[i] = src[i];
    const float* P = poses + p*12;
    float P0 = P[0], P1 = P[1], P2 = P[2],  P3 = P[3];
    float P4 = P[4], P5 = P[5], P6 = P[6],  P7 = P[7];
    float P8 = P[8], P9 = P[9], P10 = P[10], P11 = P[11];
    __syncthreads();

    for (int it = 0; it < PTS_BLK/256; it++) {
        int ptl = r0 + it*256 + tid;
        float4 pv = pts[base_pt + ptl];
        float px = pv.x, py = pv.y, pz = pv.z;
        float c0 = fmaf(P0,px, fmaf(P1,py, fmaf(P2,pz, P3)));
        float c1 = fmaf(P4,px, fmaf(P5,py, fmaf(P6,pz, P7)));
        float c2 = fmaf(P8,px, fmaf(P9,py, fmaf(P10,pz, P11)));
        float rz = __builtin_amdgcn_rcpf(c2);
        float gx = fminf(fmaxf((1.0254f*c0 + 0.5f*c2)*rz, 0.f), 1.f)*2.f - 1.f;
        float gy = fminf(fmaxf((1.0254f*c1 + 0.5f*c2)*rz, 0.f), 1.f)*2.f - 1.f;
        float ixp = ((gx + 1.f)*64.f - 1.f)*0.5f + 1.f;
        float iyp = ((gy + 1.f)*64.f - 1.f)*0.5f + 1.f;
        float xf = floorf(ixp), yf = floorf(iyp);
        float wx = ixp - xf, wy = iyp - yf;
        int x0p = (int)xf, y0p = (int)yf;     // [0,64]
        const uint2* e = tex + y0p*66 + x0p;
        uint2 e00 = e[0], e01 = e[1], e10 = e[66], e11 = e[67];
        float wy0 = 1.f - wy, wy1 = wy;
        float w0x = 1.f - wx, w1x = wx;
        float tl0 = fmaf(wy0, bflo(e00.x), wy1*bflo(e10.x));
        float tl1 = fmaf(wy0, bfhi(e00.x), wy1*bfhi(e10.x));
        float tl2 = fmaf(wy0, bflo(e00.y), wy1*bflo(e10.y));
        float tr0 = fmaf(wy0, bflo(e01.x), wy1*bflo(e11.x));
        float tr1 = fmaf(wy0, bfhi(e01.x), wy1*bfhi(e11.x));
        float tr2 = fmaf(wy0, bflo(e01.y), wy1*bflo(e11.y));
        float f0 = fmaf(w0x, tl0, w1x*tr0);
        float f1 = fmaf(w0x, tl1, w1x*tr1);
        float f2 = fmaf(w0x, tl2, w1x*tr2);
        uint2 av;
        av.x = bf16pk(f0, f1);
        av.y = (unsigned)bf16rne(f2);
        *(uint2*)(feats + ((size_t)p*chunk_pts + ptl)*4) = av;   // 8B/plane-point
    }
}

// ---- kernel 2b: MFMA MLP; gx,gy recomputed from pts (feats carries f0,f1,f2) ----
__global__ __launch_bounds__(256) void k_mlp(
    const unsigned short* __restrict__ feats, const float4* __restrict__ pts,
    const float* __restrict__ poses,
    const float* __restrict__ b1, const unsigned short* __restrict__ w1e,
    const unsigned short* __restrict__ w2e, const float* __restrict__ b2e,
    unsigned short* __restrict__ colors, float* __restrict__ dens,
    int base_pt, int chunk_pts)
{
    __shared__ __align__(16) unsigned short smem[4][4608];
    __shared__ float pls[384];
    int tid = threadIdx.x;
    int wv = tid >> 6, lane = tid & 63;
    int n = lane & 15, q = lane >> 4;
    int wlocal = blockIdx.x*256 + wv*64;
    for (int i = tid; i < 384; i += 256) pls[i] = poses[i];
    __syncthreads();

    float px[4], py[4], pz[4];
#pragma unroll
    for (int t = 0; t < 4; t++) {
        float4 pv = pts[base_pt + wlocal + t*16 + n];
        px[t] = pv.x; py[t] = pv.y; pz[t] = pv.z;
    }

    f32x4 acc[4][4];
#pragma unroll
    for (int t = 0; t < 4; t++)
#pragma unroll
        for (int nt = 0; nt < 4; nt++) {
            float bv = b1[nt*16 + n];
            acc[t][nt] = (f32x4){bv, bv, bv, bv};
        }

    for (int s = 0; s < 8; s++) {
        short8 bf[4];
#pragma unroll
        for (int nt = 0; nt < 4; nt++)
            bf[nt] = *(const short8*)(w1e + (nt*16 + n)*256 + s*32 + q*8);
        int plane = s*4 + q;
        const float* P = pls + plane*12;
#pragma unroll
        for (int t = 0; t < 4; t++) {
            uint2 fv = *(const uint2*)(feats + ((size_t)plane*chunk_pts + wlocal + t*16 + n)*4);
            float c0 = fmaf(P[0],px[t], fmaf(P[1],py[t], fmaf(P[2],pz[t], P[3])));
            float c1 = fmaf(P[4],px[t], fmaf(P[5],py[t], fmaf(P[6],pz[t], P[7])));
            float c2 = fmaf(P[8],px[t], fmaf(P[9],py[t], fmaf(P[10],pz[t], P[11])));
            float rz = __builtin_amdgcn_rcpf(c2);
            float gx = fminf(fmaxf((1.0254f*c0 + 0.5f*c2)*rz, 0.f), 1.f)*2.f - 1.f;
            float gy = fminf(fmaxf((1.0254f*c1 + 0.5f*c2)*rz, 0.f), 1.f)*2.f - 1.f;
            union { short8 s8; uint4 u; } av;
            av.u.x = fv.x;                                              // f0,f1
            av.u.y = (fv.y & 0xffffu) | ((unsigned)bf16rne(gx) << 16);  // f2,gx
            av.u.z = (unsigned)bf16rne(gy);                             // gy,0
            av.u.w = 0u;
#pragma unroll
            for (int nt = 0; nt < 4; nt++)
                acc[t][nt] = __builtin_amdgcn_mfma_f32_16x16x32_bf16(av.s8, bf[nt], acc[t][nt], 0, 0, 0);
        }
    }

    unsigned short* ht = &smem[wv][0];
#pragma unroll
    for (int t = 0; t < 4; t++)
#pragma unroll
        for (int nt = 0; nt < 4; nt++)
#pragma unroll
            for (int r = 0; r < 4; r++) {
                float hv = softplus_f(acc[t][nt][r]);
                ht[(t*16 + q*4 + r)*72 + nt*16 + n] = bf16rne(hv);
            }
    short8 a2[4][2];
#pragma unroll
    for (int t = 0; t < 4; t++)
#pragma unroll
        for (int s2 = 0; s2 < 2; s2++)
            a2[t][s2] = *(const short8*)(ht + (t*16 + n)*72 + s2*32 + q*8);
    // no __syncthreads: aliasing is wave-local; DS pipe in-order per wave

    f32x4 acc2[4][3];
#pragma unroll
    for (int t = 0; t < 4; t++)
#pragma unroll
        for (int nt = 0; nt < 3; nt++) {
            float bv = b2e[nt*16 + n];
            acc2[t][nt] = (f32x4){bv, bv, bv, bv};
        }
    short8 b2f[3][2];
#pragma unroll
    for (int nt = 0; nt < 3; nt++)
#pragma unroll
        for (int s2 = 0; s2 < 2; s2++)
            b2f[nt][s2] = *(const short8*)(w2e + (nt*16 + n)*64 + s2*32 + q*8);
#pragma unroll
    for (int t = 0; t < 4; t++)
#pragma unroll
        for (int nt = 0; nt < 3; nt++)
#pragma unroll
            for (int s2 = 0; s2 < 2; s2++)
                acc2[t][nt] = __builtin_amdgcn_mfma_f32_16x16x32_bf16(a2[t][s2], b2f[nt][s2], acc2[t][nt], 0, 0, 0);

    float* ot = (float*)&smem[wv][0];
#pragma unroll
    for (int t = 0; t < 4; t++)
#pragma unroll
        for (int nt = 0; nt < 3; nt++) {
            int col = nt*16 + n;
#pragma unroll
            for (int r = 0; r < 4; r++) {
                float v = acc2[t][nt][r];
                int row = t*16 + q*4 + r;
                if (col == 0) ot[row*34 + 32] = v;
                else if (col <= 32) {
                    float sg = sigmoid_f(v);
                    ot[row*34 + (col-1)] = fmaf(sg, 1.002f, -0.001f);
                }
            }
        }
    unsigned* cgu = (unsigned*)(colors + (size_t)(base_pt + wlocal)*32);
    for (int i = 0; i < 16; i++) {
        int ui = i*64 + lane;
        int pt = ui >> 4, ch = (ui & 15)*2;
        cgu[ui] = bf16pk(ot[pt*34 + ch], ot[pt*34 + ch + 1]);
    }
    dens[base_pt + wlocal + lane] = ot[lane*34 + 32];
}

// ---- kernel 3: coarse march + pdf + importance samples (wave per ray) ----
__global__ __launch_bounds__(256) void k_imp(const float* __restrict__ u, float* ws) {
    __shared__ float zl[4][48];
    __shared__ float cdfl[4][46];
    int tid = threadIdx.x;
    int wv = tid >> 6, lane = tid & 63;
    int r = blockIdx.x*4 + wv;
    const float* z   = ws + OFF_DC + (size_t)r*48;
    const float* den = ws + OFF_SC + (size_t)r*48;
    float zv = 0.f, dv = 0.f;
    if (lane < 48) { zv = z[lane]; dv = den[lane]; zl[wv][lane] = zv; }
    float zn  = __shfl_down(zv, 1);
    float dnn = __shfl_down(dv, 1);
    float alpha = 0.f, f = 1.f;
    if (lane < 47) {
        float sp = softplus_f(0.5f*(dv + dnn) - 1.f);
        alpha = 1.f - __expf(-sp*(zn - zv));
        f = 1.f - alpha + 1e-10f;
    }
    float v = f;
    for (int off = 1; off < 64; off <<= 1) { float o = __shfl_up(v, off); if (lane >= off) v *= o; }
    float T = __shfl_up(v, 1); if (lane == 0) T = 1.f;
    float w = alpha*T;
    float wn1 = __shfl_down(w, 1), wn2 = __shfl_down(w, 2);
    float pw = 0.f;
    if (lane < 45) pw = 0.5f*(fmaxf(w, wn1) + fmaxf(wn1, wn2)) + 0.01f + 1e-5f;
    float s = pw;
    for (int off = 1; off < 64; off <<= 1) { float o = __shfl_up(s, off); if (lane >= off) s += o; }
    float csum = __shfl(s, 63);
    if (lane < 45) cdfl[wv][lane+1] = s/csum;
    if (lane == 63) cdfl[wv][0] = 0.f;
    __syncthreads();
    if (lane < 48) {
        float uu = u[(size_t)r*48 + lane];
        int lo = 0, hi = 46;
        while (lo < hi) { int mid = (lo+hi)>>1; if (uu >= cdfl[wv][mid]) lo = mid+1; else hi = mid; }
        int below = max(lo-1, 0), above = min(lo, 45);
        float cb = cdfl[wv][below], ca = cdfl[wv][above];
        float zb = zl[wv][below],   za = zl[wv][above];
        float dn2 = ca - cb; if (dn2 < 1e-5f) dn2 = 1.f;
        ws[OFF_DF + (size_t)r*48 + lane] = zb + (uu - cb)/dn2*(za - zb);
    }
}

// ---- kernel 5: fused sort + march + color accumulation (wave per ray) ----
__global__ __launch_bounds__(256) void k_final(float* __restrict__ out, const float* __restrict__ ws,
                                               const unsigned short* __restrict__ cC,
                                               const unsigned short* __restrict__ cF)
{
    __shared__ float kd[4][96];
    __shared__ float kden[4][96];
    __shared__ float sdl[4][96];
    __shared__ float sdenl[4][96];
    __shared__ int   sidxl[4][96];
    __shared__ float warr[4][96];
    __shared__ float earr[4][96];
    int tid = threadIdx.x;
    int wv = tid >> 6, lane = tid & 63;
    int r = blockIdx.x*4 + wv;
    const float* dc = ws + OFF_DC + (size_t)r*48;
    const float* df = ws + OFF_DF + (size_t)r*48;
    const float* sc = ws + OFF_SC + (size_t)r*48;
    const float* sf = ws + OFF_SF + (size_t)r*48;
    for (int i = lane; i < 96; i += 64) {
        float d, dn;
        if (i < 48) { d = dc[i]; dn = sc[i]; }
        else        { d = df[i-48]; dn = sf[i-48]; }
        kd[wv][i] = d; kden[wv][i] = dn;
    }
    __syncthreads();
    for (int i = lane; i < 96; i += 64) {
        float d = kd[wv][i];
        int rank = 0;
        for (int j = 0; j < 96; j++) {
            float dj = kd[wv][j];
            rank += (int)((dj < d) | ((dj == d) & (j < i)));
        }
        sdl[wv][rank] = d; sdenl[wv][rank] = kden[wv][i]; sidxl[wv][rank] = i;
    }
    __syncthreads();
    int i2 = 2*lane;
    float a0=0.f, f0=1.f, a1=0.f, f1=1.f, d0=0.f, d1=0.f, d2=0.f;
    if (i2 < 95) {
        d0 = sdl[wv][i2]; d1 = sdl[wv][i2+1];
        float sp = softplus_f(0.5f*(sdenl[wv][i2] + sdenl[wv][i2+1]) - 1.f);
        a0 = 1.f - __expf(-sp*(d1 - d0)); f0 = 1.f - a0 + 1e-10f;
    }
    if (i2+1 < 95) {
        d2 = sdl[wv][i2+2];
        float sp = softplus_f(0.5f*(sdenl[wv][i2+1] + sdenl[wv][i2+2]) - 1.f);
        a1 = 1.f - __expf(-sp*(d2 - d1)); f1 = 1.f - a1 + 1e-10f;
    }
    float p = f0*f1, v = p;
    for (int off = 1; off < 64; off <<= 1) { float o = __shfl_up(v, off); if (lane >= off) v *= o; }
    float excl = __shfl_up(v, 1); if (lane == 0) excl = 1.f;
    float w0 = a0*excl, w1 = a1*excl*f0;
    if (i2   < 96) warr[wv][i2]   = w0;
    if (i2+1 < 96) warr[wv][i2+1] = w1;
    float wsm = w0 + w1;
    float dsm = w0*0.5f*(d0+d1) + w1*0.5f*(d1+d2);
    for (int off = 32; off; off >>= 1) { wsm += __shfl_xor(wsm, off); dsm += __shfl_xor(dsm, off); }
    __syncthreads();
    for (int i = lane; i < 96; i += 64) {
        float wp = (i > 0)  ? warr[wv][i-1] : 0.f;
        float wc = (i < 95) ? warr[wv][i]   : 0.f;
        earr[wv][sidxl[wv][i]] = 0.5f*(wp + wc);
    }
    __syncthreads();
    int ch = lane & 31, half = lane >> 5;
    const unsigned short* cbase = (half ? cF : cC) + ((size_t)r*48)*32 + ch;
    const float* eb = &earr[wv][half*48];
    float a = 0.f;
    for (int jj = 0; jj < 48; jj++)
        a = fmaf(eb[jj], bf2f(cbase[(size_t)jj*32]), a);
    a += __shfl_xor(a, 32);
    if (lane < 32) out[(size_t)r*34 + lane] = 2.f*a - 1.f;
    if (lane == 0) {
        float gmn = ws[OFF_MINMAX];
        float gmx = ws[OFF_MINMAX + 1];
        float depth = dsm/wsm;
        if (depth != depth) depth = __builtin_inff();
        depth = fminf(fmaxf(depth, gmn), gmx);
        out[(size_t)r*34 + 32] = depth;
        out[(size_t)r*34 + 33] = wsm;
    }
}

extern "C" void kernel_launch(void* const* d_in, const int* in_sizes, int n_in,
                              void* d_out, int out_size, void* d_ws, size_t ws_size,
                              hipStream_t stream) {
    const float* planes = (const float*)d_in[0];
    const float* ro     = (const float*)d_in[1];
    const float* rd     = (const float*)d_in[2];
    const float* noise  = (const float*)d_in[3];
    const float* u      = (const float*)d_in[4];
    const float* W1     = (const float*)d_in[5];
    const float* b1     = (const float*)d_in[6];
    const float* W2     = (const float*)d_in[7];
    const float* b2     = (const float*)d_in[8];
    float* ws  = (float*)d_ws;
    float* out = (float*)d_out;
    const unsigned short* w1e = (const unsigned short*)(ws + OFF_W1E);
    const unsigned short* w2e = (const unsigned short*)(ws + OFF_W2E);
    uint2* st = (uint2*)(ws + OFF_ST);
    float4* pts = (float4*)(ws + OFF_PTS);
    unsigned short* cC = (unsigned short*)(ws + OFF_CC);
    unsigned short* cF = (unsigned short*)(ws + OFF_CF);
    unsigned short* feats = (unsigned short*)(ws + OFF_FEATS);

    // chunk the feats buffer (64 floats/point) to whatever ws_size allows
    long cap = (long)(ws_size/sizeof(float)) - OFF_FEATS;
    int chunk = NPTS;
    while ((long)chunk*64 > cap && chunk > 3*PTS_BLK) chunk >>= 1;
    int nch = NPTS/chunk;

    hipLaunchKernelGGL(k_init,   dim3(1),    dim3(256), 0, stream, ws, W1, W2, b2, noise);
    hipLaunchKernelGGL(k_repack, dim3((ST_TOTAL + 255)/256), dim3(256), 0, stream, planes, st);
    hipLaunchKernelGGL(k_pts,    dim3(NPTS/256), dim3(256), 0, stream,
                       noise, ro, rd, (const float*)nullptr, ws + OFF_DC, pts, 1);
    for (int c = 0; c < nch; c++) {
        hipLaunchKernelGGL(k_gather, dim3((chunk/PTS_BLK)*32), dim3(256), 0, stream,
                           st, pts, ws + OFF_POSES, feats, c*chunk, chunk);
        hipLaunchKernelGGL(k_mlp,    dim3(chunk/256), dim3(256), 0, stream,
                           feats, pts, ws + OFF_POSES,
                           b1, w1e, w2e, ws + OFF_B2E, cC, ws + OFF_SC, c*chunk, chunk);
    }
    hipLaunchKernelGGL(k_imp, dim3(NRAYS/4), dim3(256), 0, stream, u, ws);
    hipLaunchKernelGGL(k_pts, dim3(NPTS/256), dim3(256), 0, stream,
                       noise, ro, rd, ws + OFF_DF, ws + OFF_DC, pts, 0);
    for (int c = 0; c < nch; c++) {
        hipLaunchKernelGGL(k_gather, dim3((chunk/PTS_BLK)*32), dim3(256), 0, stream,
                           st, pts, ws + OFF_POSES, feats, c*chunk, chunk);
        hipLaunchKernelGGL(k_mlp,    dim3(chunk/256), dim3(256), 0, stream,
                           feats, pts, ws + OFF_POSES,
                           b1, w1e, w2e, ws + OFF_B2E, cF, ws + OFF_SF, c*chunk, chunk);
    }
    hipLaunchKernelGGL(k_final, dim3(NRAYS/4), dim3(256), 0, stream, out, ws, cC, cF);
}

// Round 18
// 322.329 us; speedup vs baseline: 1.4254x; 1.0347x over previous
//
#include <hip/hip_runtime.h>
#include <math.h>

#define B_   2
#define N_   4096
#define S_   48
#define NPL  32
#define NRAYS (B_*N_)          // 8192
#define NPTS  (NRAYS*S_)       // 393216
#define DELTA_ (2.0f/47.0f)

#define ST_ENT   4356                   // 66*66 single-texel entries per plane (8B each)
#define ST_TOTAL (64*ST_ENT)            // 278784
#define PTS_BLK  12288                  // points per gather block (divides NPTS/2)

// ---- workspace layout (float offsets) ----
#define OFF_POSES  0                    // 384
#define OFF_MINMAX 384                  // 2 floats (gmin, gmax)
#define OFF_W1E    512                  // 64*256 bf16
#define OFF_W2E    8704                 // 48*64 bf16
#define OFF_B2E    10240                // 48 floats
#define OFF_ST     16384                // single-texel planes: ST_TOTAL uint2 -> ends 573952
#define OFF_PTS    573952               // float4 per point: NPTS*4 -> ends 2146816
#define OFF_DC     2146816              // depths_c [NPTS]
#define OFF_DF     2540032
#define OFF_SC     2933248
#define OFF_SF     3326464
#define OFF_CC     3719680              // colors_c bf16 [NPTS*32] -> ends 10011136
#define OFF_CF     10011136             // colors_f bf16 -> ends 16302592
#define OFF_FEATS  16302592             // feats: chunk*64 floats (8B/plane-point)
// gxy buffer follows feats: chunk*32 floats (4B/plane-point)

typedef __attribute__((ext_vector_type(8))) short short8;
typedef __attribute__((ext_vector_type(4))) float f32x4;

__device__ __forceinline__ float softplus_f(float x) {
    return fmaxf(x, 0.f) + __logf(1.f + __expf(-fabsf(x)));
}
__device__ __forceinline__ float sigmoid_f(float x) {
    return __builtin_amdgcn_rcpf(1.f + __expf(-x));
}
__device__ __forceinline__ unsigned short bf16rne(float x) {
    unsigned u = __float_as_uint(x);
    u += 0x7FFFu + ((u >> 16) & 1u);
    return (unsigned short)(u >> 16);
}
__device__ __forceinline__ unsigned bf16pk(float lo, float hi) {
    return (unsigned)bf16rne(lo) | ((unsigned)bf16rne(hi) << 16);
}
__device__ __forceinline__ float bf2f(unsigned short v) {
    return __uint_as_float(((unsigned)v) << 16);
}
__device__ __forceinline__ float bflo(unsigned u) { return __uint_as_float(u << 16); }
__device__ __forceinline__ float bfhi(unsigned u) { return __uint_as_float(u & 0xffff0000u); }

__device__ void mul3(const double* a, const double* b, double* o) {
    for (int i = 0; i < 3; i++)
        for (int j = 0; j < 3; j++) {
            double s = 0.0;
            for (int k = 0; k < 3; k++) s += a[i*3+k]*b[k*3+j];
            o[i*3+j] = s;
        }
}

// ---- kernel 0: poses (double math), minmax reduction (no atomics), bf16 weights ----
__global__ void k_init(float* ws, const float* __restrict__ W1,
                       const float* __restrict__ W2, const float* __restrict__ b2,
                       const float* __restrict__ noise) {
    __shared__ float redmn[4], redmx[4];
    int t = threadIdx.x;
    if (t < 32) {
        double y = 1.0 - (t/31.0)*2.0;
        double rr = sqrt(fmax(1.0 - y*y, 0.0));
        double golden = M_PI*(sqrt(5.0) - 1.0);
        double th = golden*(double)t;
        double x = cos(th)*rr, z = sin(th)*rr;
        double phi   = atan2(z, sqrt(x*x + y*y));   // radians treated as degrees (faithful)
        double theta = atan2(y, x);
        double p  = phi/180.0*M_PI;
        double tt = theta/180.0*M_PI;
        double e  = 90.0/180.0*M_PI;
        double cp = cos(p), sp = sin(p), ct = cos(tt), st = sin(tt);
        double ce = cos(e), se = sin(e);
        double Ph[9] = {1,0,0,  0,cp,-sp,  0,sp,cp};
        double Th[9] = {ct,0,-st,  0,1,0,  st,0,ct};
        double Et[9] = {ce,se,0,  -se,ce,0,  0,0,1};
        double M3[9] = {-1,0,0,  0,0,1,  0,1,0};
        double A[9], Bm[9], R[9];
        mul3(Th, Ph, A);
        mul3(Et, A, Bm);
        mul3(M3, Bm, R);
        double radius = -1.307;
        double tv0 = radius*R[2], tv1 = radius*R[5], tv2 = radius*R[8];
        double Rf[9] = {-R[0],R[1],R[2], -R[3],R[4],R[5], -R[6],R[7],R[8]};
        float* P = ws + OFF_POSES + t*12;
        for (int j = 0; j < 3; j++) {
            double r0 = Rf[0*3+j], r1 = Rf[1*3+j], r2 = Rf[2*3+j];
            P[j*4+0] = (float)r0;
            P[j*4+1] = (float)r1;
            P[j*4+2] = (float)r2;
            P[j*4+3] = (float)(-(r0*tv0 + r1*tv1 + r2*tv2));
        }
    }
    unsigned short* w1e = (unsigned short*)(ws + OFF_W1E);
    for (int idx = t; idx < 64*256; idx += 256) {
        int n = idx >> 8, k = idx & 255;
        int p = k >> 3, f = k & 7;
        float v = 0.f;
        if (f < 3)      v = W1[(3*p+f)*64 + n];
        else if (f < 5) v = W1[(96 + 2*p + (f-3))*64 + n];
        w1e[idx] = bf16rne(v);
    }
    unsigned short* w2e = (unsigned short*)(ws + OFF_W2E);
    for (int idx = t; idx < 48*64; idx += 256) {
        int n = idx >> 6, k = idx & 63;
        float v = (n < 33) ? W2[k*33 + n] : 0.f;
        w2e[idx] = bf16rne(v);
    }
    for (int idx = t; idx < 48; idx += 256)
        ws[OFF_B2E + idx] = (idx < 33) ? b2[idx] : 0.f;

    // minmax over noise col 0 / col 47 (one block, no atomics)
    float mn = 1e30f, mx = -1e30f;
    for (int r = t; r < NRAYS; r += 256) {
        float n0  = noise[(size_t)r*48];
        float n47 = noise[(size_t)r*48 + 47];
        mn = fminf(mn, 0.5f + n0*DELTA_);
        mx = fmaxf(mx, 0.5f + 47.f*DELTA_ + n47*DELTA_);
    }
    for (int off = 32; off > 0; off >>= 1) {
        mn = fminf(mn, __shfl_down(mn, off));
        mx = fmaxf(mx, __shfl_down(mx, off));
    }
    if ((t & 63) == 0) { redmn[t >> 6] = mn; redmx[t >> 6] = mx; }
    __syncthreads();
    if (t == 0) {
        ws[OFF_MINMAX]     = fminf(fminf(redmn[0], redmn[1]), fminf(redmn[2], redmn[3]));
        ws[OFF_MINMAX + 1] = fmaxf(fmaxf(redmx[0], redmx[1]), fmaxf(redmx[2], redmx[3]));
    }
}

// ---- kernel 1: repack planes to guard-padded bf16 single texels (8B) ----
__global__ __launch_bounds__(256) void k_repack(const float* __restrict__ planes, uint2* __restrict__ st) {
    int idx = blockIdx.x*256 + threadIdx.x;
    if (idx >= ST_TOTAL) return;
    int bp = idx / ST_ENT;
    int rem = idx - bp*ST_ENT;
    int j = rem / 66, i = rem - j*66;
    unsigned ux = 0, uy = 0;
    if (j >= 1 && j <= 64 && i >= 1 && i <= 64) {
        int b = bp >> 5, p = bp & 31;
        const float* src = planes + (((size_t)b*96 + 3*p)*64 + (j-1))*64 + (i-1);
        ux = bf16pk(src[0], src[4096]);
        uy = (unsigned)bf16rne(src[8192]);
    }
    st[idx] = make_uint2(ux, uy);
}

// ---- kernel 1b: point prepass — position+depth once per point ----
__global__ __launch_bounds__(256) void k_pts(
    const float* __restrict__ noise, const float* __restrict__ ro,
    const float* __restrict__ rd, const float* __restrict__ dfin,
    float* __restrict__ dcout, float4* __restrict__ pts, int coarse)
{
    int pt = blockIdx.x*256 + threadIdx.x;
    if (pt >= NPTS) return;
    int ray = pt / S_;
    float depth;
    if (coarse) {
        int j = pt - ray*S_;
        depth = 0.5f + (float)j*DELTA_ + noise[pt]*DELTA_;
        dcout[pt] = depth;
    } else depth = dfin[pt];
    float px = fmaf(depth, rd[ray*3+0], ro[ray*3+0]);
    float py = fmaf(depth, rd[ray*3+1], ro[ray*3+1]);
    float pz = fmaf(depth, rd[ray*3+2], ro[ray*3+2]);
    pts[pt] = make_float4(px, py, pz, depth);
}

// ---- kernel 2a: LDS-staged gather; writes f-triple (8B) + gxy pair (4B) ----
__global__ __launch_bounds__(256) void k_gather(
    const uint2* __restrict__ st, const float4* __restrict__ pts,
    const float* __restrict__ poses,
    unsigned short* __restrict__ feats, unsigned* __restrict__ gxy,
    int base_pt, int chunk_pts)
{
    __shared__ uint2 tex[ST_ENT];       // 34848 B
    int tid = threadIdx.x;
    int p  = blockIdx.x & 31;           // plane
    int pr = blockIdx.x >> 5;           // point-range index within chunk
    int r0 = pr*PTS_BLK;
    int b = (base_pt + r0 >= NPTS/2) ? 1 : 0;   // PTS_BLK divides NPTS/2
    const uint2* src = st + (size_t)(b*32 + p)*ST_ENT;
    for (int i = tid; i < ST_ENT; i += 256) tex[i] = src[i];
    const float* P = poses + p*12;
    float P0 = P[0], P1 = P[1], P2 = P[2],  P3 = P[3];
    float P4 = P[4], P5 = P[5], P6 = P[6],  P7 = P[7];
    float P8 = P[8], P9 = P[9], P10 = P[10], P11 = P[11];
    __syncthreads();

    for (int it = 0; it < PTS_BLK/256; it++) {
        int ptl = r0 + it*256 + tid;
        float4 pv = pts[base_pt + ptl];
        float px = pv.x, py = pv.y, pz = pv.z;
        float c0 = fmaf(P0,px, fmaf(P1,py, fmaf(P2,pz, P3)));
        float c1 = fmaf(P4,px, fmaf(P5,py, fmaf(P6,pz, P7)));
        float c2 = fmaf(P8,px, fmaf(P9,py, fmaf(P10,pz, P11)));
        float rz = __builtin_amdgcn_rcpf(c2);
        float gx = fminf(fmaxf((1.0254f*c0 + 0.5f*c2)*rz, 0.f), 1.f)*2.f - 1.f;
        float gy = fminf(fmaxf((1.0254f*c1 + 0.5f*c2)*rz, 0.f), 1.f)*2.f - 1.f;
        float ixp = ((gx + 1.f)*64.f - 1.f)*0.5f + 1.f;
        float iyp = ((gy + 1.f)*64.f - 1.f)*0.5f + 1.f;
        float xf = floorf(ixp), yf = floorf(iyp);
        float wx = ixp - xf, wy = iyp - yf;
        int x0p = (int)xf, y0p = (int)yf;     // [0,64]
        const uint2* e = tex + y0p*66 + x0p;
        uint2 e00 = e[0], e01 = e[1], e10 = e[66], e11 = e[67];
        float wy0 = 1.f - wy, wy1 = wy;
        float w0x = 1.f - wx, w1x = wx;
        float tl0 = fmaf(wy0, bflo(e00.x), wy1*bflo(e10.x));
        float tl1 = fmaf(wy0, bfhi(e00.x), wy1*bfhi(e10.x));
        float tl2 = fmaf(wy0, bflo(e00.y), wy1*bflo(e10.y));
        float tr0 = fmaf(wy0, bflo(e01.x), wy1*bflo(e11.x));
        float tr1 = fmaf(wy0, bfhi(e01.x), wy1*bfhi(e11.x));
        float tr2 = fmaf(wy0, bflo(e01.y), wy1*bflo(e11.y));
        float f0 = fmaf(w0x, tl0, w1x*tr0);
        float f1 = fmaf(w0x, tl1, w1x*tr1);
        float f2 = fmaf(w0x, tl2, w1x*tr2);
        size_t slot = (size_t)p*chunk_pts + ptl;
        uint2 av;
        av.x = bf16pk(f0, f1);
        av.y = (unsigned)bf16rne(f2);
        *(uint2*)(feats + slot*4) = av;
        gxy[slot] = bf16pk(gx, gy);
    }
}

// ---- kernel 2b: MFMA MLP — pure GEMM, A-fragments from feats+gxy ----
__global__ __launch_bounds__(256) void k_mlp(
    const unsigned short* __restrict__ feats, const unsigned* __restrict__ gxy,
    const float* __restrict__ b1, const unsigned short* __restrict__ w1e,
    const unsigned short* __restrict__ w2e, const float* __restrict__ b2e,
    unsigned short* __restrict__ colors, float* __restrict__ dens,
    int base_pt, int chunk_pts)
{
    __shared__ __align__(16) unsigned short smem[4][4608];
    int tid = threadIdx.x;
    int wv = tid >> 6, lane = tid & 63;
    int n = lane & 15, q = lane >> 4;
    int wlocal = blockIdx.x*256 + wv*64;

    f32x4 acc[4][4];
#pragma unroll
    for (int t = 0; t < 4; t++)
#pragma unroll
        for (int nt = 0; nt < 4; nt++) {
            float bv = b1[nt*16 + n];
            acc[t][nt] = (f32x4){bv, bv, bv, bv};
        }

    for (int s = 0; s < 8; s++) {
        short8 bf[4];
#pragma unroll
        for (int nt = 0; nt < 4; nt++)
            bf[nt] = *(const short8*)(w1e + (nt*16 + n)*256 + s*32 + q*8);
        int plane = s*4 + q;
#pragma unroll
        for (int t = 0; t < 4; t++) {
            size_t slot = (size_t)plane*chunk_pts + wlocal + t*16 + n;
            uint2 fv = *(const uint2*)(feats + slot*4);
            unsigned g = gxy[slot];
            union { short8 s8; uint4 u; } av;
            av.u.x = fv.x;                                      // f0,f1
            av.u.y = (fv.y & 0xffffu) | (g << 16);              // f2,gx
            av.u.z = g >> 16;                                   // gy,0
            av.u.w = 0u;
#pragma unroll
            for (int nt = 0; nt < 4; nt++)
                acc[t][nt] = __builtin_amdgcn_mfma_f32_16x16x32_bf16(av.s8, bf[nt], acc[t][nt], 0, 0, 0);
        }
    }

    unsigned short* ht = &smem[wv][0];
#pragma unroll
    for (int t = 0; t < 4; t++)
#pragma unroll
        for (int nt = 0; nt < 4; nt++)
#pragma unroll
            for (int r = 0; r < 4; r++) {
                float hv = softplus_f(acc[t][nt][r]);
                ht[(t*16 + q*4 + r)*72 + nt*16 + n] = bf16rne(hv);
            }
    short8 a2[4][2];
#pragma unroll
    for (int t = 0; t < 4; t++)
#pragma unroll
        for (int s2 = 0; s2 < 2; s2++)
            a2[t][s2] = *(const short8*)(ht + (t*16 + n)*72 + s2*32 + q*8);
    // no __syncthreads: aliasing is wave-local; DS pipe in-order per wave

    f32x4 acc2[4][3];
#pragma unroll
    for (int t = 0; t < 4; t++)
#pragma unroll
        for (int nt = 0; nt < 3; nt++) {
            float bv = b2e[nt*16 + n];
            acc2[t][nt] = (f32x4){bv, bv, bv, bv};
        }
    short8 b2f[3][2];
#pragma unroll
    for (int nt = 0; nt < 3; nt++)
#pragma unroll
        for (int s2 = 0; s2 < 2; s2++)
            b2f[nt][s2] = *(const short8*)(w2e + (nt*16 + n)*64 + s2*32 + q*8);
#pragma unroll
    for (int t = 0; t < 4; t++)
#pragma unroll
        for (int nt = 0; nt < 3; nt++)
#pragma unroll
            for (int s2 = 0; s2 < 2; s2++)
                acc2[t][nt] = __builtin_amdgcn_mfma_f32_16x16x32_bf16(a2[t][s2], b2f[nt][s2], acc2[t][nt], 0, 0, 0);

    float* ot = (float*)&smem[wv][0];
#pragma unroll
    for (int t = 0; t < 4; t++)
#pragma unroll
        for (int nt = 0; nt < 3; nt++) {
            int col = nt*16 + n;
#pragma unroll
            for (int r = 0; r < 4; r++) {
                float v = acc2[t][nt][r];
                int row = t*16 + q*4 + r;
                if (col == 0) ot[row*34 + 32] = v;
                else if (col <= 32) {
                    float sg = sigmoid_f(v);
                    ot[row*34 + (col-1)] = fmaf(sg, 1.002f, -0.001f);
                }
            }
        }
    unsigned* cgu = (unsigned*)(colors + (size_t)(base_pt + wlocal)*32);
    for (int i = 0; i < 16; i++) {
        int ui = i*64 + lane;
        int pt = ui >> 4, ch = (ui & 15)*2;
        cgu[ui] = bf16pk(ot[pt*34 + ch], ot[pt*34 + ch + 1]);
    }
    dens[base_pt + wlocal + lane] = ot[lane*34 + 32];
}

// ---- kernel 3: coarse march + pdf + importance samples (wave per ray) ----
__global__ __launch_bounds__(256) void k_imp(const float* __restrict__ u, float* ws) {
    __shared__ float zl[4][48];
    __shared__ float cdfl[4][46];
    int tid = threadIdx.x;
    int wv = tid >> 6, lane = tid & 63;
    int r = blockIdx.x*4 + wv;
    const float* z   = ws + OFF_DC + (size_t)r*48;
    const float* den = ws + OFF_SC + (size_t)r*48;
    float zv = 0.f, dv = 0.f;
    if (lane < 48) { zv = z[lane]; dv = den[lane]; zl[wv][lane] = zv; }
    float zn  = __shfl_down(zv, 1);
    float dnn = __shfl_down(dv, 1);
    float alpha = 0.f, f = 1.f;
    if (lane < 47) {
        float sp = softplus_f(0.5f*(dv + dnn) - 1.f);
        alpha = 1.f - __expf(-sp*(zn - zv));
        f = 1.f - alpha + 1e-10f;
    }
    float v = f;
    for (int off = 1; off < 64; off <<= 1) { float o = __shfl_up(v, off); if (lane >= off) v *= o; }
    float T = __shfl_up(v, 1); if (lane == 0) T = 1.f;
    float w = alpha*T;
    float wn1 = __shfl_down(w, 1), wn2 = __shfl_down(w, 2);
    float pw = 0.f;
    if (lane < 45) pw = 0.5f*(fmaxf(w, wn1) + fmaxf(wn1, wn2)) + 0.01f + 1e-5f;
    float s = pw;
    for (int off = 1; off < 64; off <<= 1) { float o = __shfl_up(s, off); if (lane >= off) s += o; }
    float csum = __shfl(s, 63);
    if (lane < 45) cdfl[wv][lane+1] = s/csum;
    if (lane == 63) cdfl[wv][0] = 0.f;
    __syncthreads();
    if (lane < 48) {
        float uu = u[(size_t)r*48 + lane];
        int lo = 0, hi = 46;
        while (lo < hi) { int mid = (lo+hi)>>1; if (uu >= cdfl[wv][mid]) lo = mid+1; else hi = mid; }
        int below = max(lo-1, 0), above = min(lo, 45);
        float cb = cdfl[wv][below], ca = cdfl[wv][above];
        float zb = zl[wv][below],   za = zl[wv][above];
        float dn2 = ca - cb; if (dn2 < 1e-5f) dn2 = 1.f;
        ws[OFF_DF + (size_t)r*48 + lane] = zb + (uu - cb)/dn2*(za - zb);
    }
}

// ---- kernel 5: fused sort + march + color accumulation (wave per ray) ----
__global__ __launch_bounds__(256) void k_final(float* __restrict__ out, const float* __restrict__ ws,
                                               const unsigned short* __restrict__ cC,
                                               const unsigned short* __restrict__ cF)
{
    __shared__ float kd[4][96];
    __shared__ float kden[4][96];
    __shared__ float sdl[4][96];
    __shared__ float sdenl[4][96];
    __shared__ int   sidxl[4][96];
    __shared__ float warr[4][96];
    __shared__ float earr[4][96];
    int tid = threadIdx.x;
    int wv = tid >> 6, lane = tid & 63;
    int r = blockIdx.x*4 + wv;
    const float* dc = ws + OFF_DC + (size_t)r*48;
    const float* df = ws + OFF_DF + (size_t)r*48;
    const float* sc = ws + OFF_SC + (size_t)r*48;
    const float* sf = ws + OFF_SF + (size_t)r*48;
    for (int i = lane; i < 96; i += 64) {
        float d, dn;
        if (i < 48) { d = dc[i]; dn = sc[i]; }
        else        { d = df[i-48]; dn = sf[i-48]; }
        kd[wv][i] = d; kden[wv][i] = dn;
    }
    __syncthreads();
    for (int i = lane; i < 96; i += 64) {
        float d = kd[wv][i];
        int rank = 0;
        for (int j = 0; j < 96; j++) {
            float dj = kd[wv][j];
            rank += (int)((dj < d) | ((dj == d) & (j < i)));
        }
        sdl[wv][rank] = d; sdenl[wv][rank] = kden[wv][i]; sidxl[wv][rank] = i;
    }
    __syncthreads();
    int i2 = 2*lane;
    float a0=0.f, f0=1.f, a1=0.f, f1=1.f, d0=0.f, d1=0.f, d2=0.f;
    if (i2 < 95) {
        d0 = sdl[wv][i2]; d1 = sdl[wv][i2+1];
        float sp = softplus_f(0.5f*(sdenl[wv][i2] + sdenl[wv][i2+1]) - 1.f);
        a0 = 1.f - __expf(-sp*(d1 - d0)); f0 = 1.f - a0 + 1e-10f;
    }
    if (i2+1 < 95) {
        d2 = sdl[wv][i2+2];
        float sp = softplus_f(0.5f*(sdenl[wv][i2+1] + sdenl[wv][i2+2]) - 1.f);
        a1 = 1.f - __expf(-sp*(d2 - d1)); f1 = 1.f - a1 + 1e-10f;
    }
    float p = f0*f1, v = p;
    for (int off = 1; off < 64; off <<= 1) { float o = __shfl_up(v, off); if (lane >= off) v *= o; }
    float excl = __shfl_up(v, 1); if (lane == 0) excl = 1.f;
    float w0 = a0*excl, w1 = a1*excl*f0;
    if (i2   < 96) warr[wv][i2]   = w0;
    if (i2+1 < 96) warr[wv][i2+1] = w1;
    float wsm = w0 + w1;
    float dsm = w0*0.5f*(d0+d1) + w1*0.5f*(d1+d2);
    for (int off = 32; off; off >>= 1) { wsm += __shfl_xor(wsm, off); dsm += __shfl_xor(dsm, off); }
    __syncthreads();
    for (int i = lane; i < 96; i += 64) {
        float wp = (i > 0)  ? warr[wv][i-1] : 0.f;
        float wc = (i < 95) ? warr[wv][i]   : 0.f;
        earr[wv][sidxl[wv][i]] = 0.5f*(wp + wc);
    }
    __syncthreads();
    int ch = lane & 31, half = lane >> 5;
    const unsigned short* cbase = (half ? cF : cC) + ((size_t)r*48)*32 + ch;
    const float* eb = &earr[wv][half*48];
    float a = 0.f;
    for (int jj = 0; jj < 48; jj++)
        a = fmaf(eb[jj], bf2f(cbase[(size_t)jj*32]), a);
    a += __shfl_xor(a, 32);
    if (lane < 32) out[(size_t)r*34 + lane] = 2.f*a - 1.f;
    if (lane == 0) {
        float gmn = ws[OFF_MINMAX];
        float gmx = ws[OFF_MINMAX + 1];
        float depth = dsm/wsm;
        if (depth != depth) depth = __builtin_inff();
        depth = fminf(fmaxf(depth, gmn), gmx);
        out[(size_t)r*34 + 32] = depth;
        out[(size_t)r*34 + 33] = wsm;
    }
}

extern "C" void kernel_launch(void* const* d_in, const int* in_sizes, int n_in,
                              void* d_out, int out_size, void* d_ws, size_t ws_size,
                              hipStream_t stream) {
    const float* planes = (const float*)d_in[0];
    const float* ro     = (const float*)d_in[1];
    const float* rd     = (const float*)d_in[2];
    const float* noise  = (const float*)d_in[3];
    const float* u      = (const float*)d_in[4];
    const float* W1     = (const float*)d_in[5];
    const float* b1     = (const float*)d_in[6];
    const float* W2     = (const float*)d_in[7];
    const float* b2     = (const float*)d_in[8];
    float* ws  = (float*)d_ws;
    float* out = (float*)d_out;
    const unsigned short* w1e = (const unsigned short*)(ws + OFF_W1E);
    const unsigned short* w2e = (const unsigned short*)(ws + OFF_W2E);
    uint2* st = (uint2*)(ws + OFF_ST);
    float4* pts = (float4*)(ws + OFF_PTS);
    unsigned short* cC = (unsigned short*)(ws + OFF_CC);
    unsigned short* cF = (unsigned short*)(ws + OFF_CF);

    // chunk: feats = chunk*64 floats, gxy = chunk*32 floats
    long cap = (long)(ws_size/sizeof(float)) - OFF_FEATS;
    int chunk = NPTS;
    while ((long)chunk*96 > cap && chunk > PTS_BLK) chunk >>= 1;
    int nch = NPTS/chunk;
    unsigned short* feats = (unsigned short*)(ws + OFF_FEATS);
    unsigned* gxy = (unsigned*)(ws + OFF_FEATS + (size_t)chunk*64);

    hipLaunchKernelGGL(k_init,   dim3(1),    dim3(256), 0, stream, ws, W1, W2, b2, noise);
    hipLaunchKernelGGL(k_repack, dim3((ST_TOTAL + 255)/256), dim3(256), 0, stream, planes, st);
    hipLaunchKernelGGL(k_pts,    dim3(NPTS/256), dim3(256), 0, stream,
                       noise, ro, rd, (const float*)nullptr, ws + OFF_DC, pts, 1);
    for (int c = 0; c < nch; c++) {
        hipLaunchKernelGGL(k_gather, dim3((chunk/PTS_BLK)*32), dim3(256), 0, stream,
                           st, pts, ws + OFF_POSES, feats, gxy, c*chunk, chunk);
        hipLaunchKernelGGL(k_mlp,    dim3(chunk/256), dim3(256), 0, stream,
                           feats, gxy, b1, w1e, w2e, ws + OFF_B2E, cC, ws + OFF_SC, c*chunk, chunk);
    }
    hipLaunchKernelGGL(k_imp, dim3(NRAYS/4), dim3(256), 0, stream, u, ws);
    hipLaunchKernelGGL(k_pts, dim3(NPTS/256), dim3(256), 0, stream,
                       noise, ro, rd, ws + OFF_DF, ws + OFF_DC, pts, 0);
    for (int c = 0; c < nch; c++) {
        hipLaunchKernelGGL(k_gather, dim3((chunk/PTS_BLK)*32), dim3(256), 0, stream,
                           st, pts, ws + OFF_POSES, feats, gxy, c*chunk, chunk);
        hipLaunchKernelGGL(k_mlp,    dim3(chunk/256), dim3(256), 0, stream,
                           feats, gxy, b1, w1e, w2e, ws + OFF_B2E, cF, ws + OFF_SF, c*chunk, chunk);
    }
    hipLaunchKernelGGL(k_final, dim3(NRAYS/4), dim3(256), 0, stream, out, ws, cC, cF);
}

// Round 19
// 313.179 us; speedup vs baseline: 1.4670x; 1.0292x over previous
//
#include <hip/hip_runtime.h>
#include <math.h>

#define B_   2
#define N_   4096
#define S_   48
#define NPL  32
#define NRAYS (B_*N_)          // 8192
#define NPTS  (NRAYS*S_)       // 393216
#define DELTA_ (2.0f/47.0f)

#define ST_ENT   4356                   // 66*66 single-texel entries per plane (8B each)
#define ST_TOTAL (64*ST_ENT)            // 278784
#define PTS_BLK  12288                  // points per gather block (divides NPTS/2)

// ---- workspace layout (float offsets) ----
#define OFF_POSES  0                    // 384
#define OFF_MINMAX 384                  // 2 floats (gmin, gmax)
#define OFF_W1E    512                  // 64*256 bf16
#define OFF_W2E    8704                 // 48*64 bf16
#define OFF_B2E    10240                // 48 floats
#define OFF_ST     16384                // single-texel planes: ST_TOTAL uint2 -> ends 573952
#define OFF_PTS    573952               // float4 per point: NPTS*4 -> ends 2146816
#define OFF_DC     2146816              // depths_c [NPTS]
#define OFF_DF     2540032
#define OFF_SC     2933248
#define OFF_SF     3326464
#define OFF_CC     3719680              // colors_c bf16 [NPTS*32] -> ends 10011136
#define OFF_CF     10011136             // colors_f bf16 -> ends 16302592
#define OFF_FEATS  16302592             // feats: chunk*64 floats (8B/plane-point); gxy follows

typedef __attribute__((ext_vector_type(8))) short short8;
typedef __attribute__((ext_vector_type(4))) float f32x4;

__device__ __forceinline__ float softplus_f(float x) {
    return fmaxf(x, 0.f) + __logf(1.f + __expf(-fabsf(x)));
}
__device__ __forceinline__ float sigmoid_f(float x) {
    return __builtin_amdgcn_rcpf(1.f + __expf(-x));
}
__device__ __forceinline__ unsigned short bf16rne(float x) {
    unsigned u = __float_as_uint(x);
    u += 0x7FFFu + ((u >> 16) & 1u);
    return (unsigned short)(u >> 16);
}
__device__ __forceinline__ unsigned bf16pk(float lo, float hi) {
    return (unsigned)bf16rne(lo) | ((unsigned)bf16rne(hi) << 16);
}
__device__ __forceinline__ float bf2f(unsigned short v) {
    return __uint_as_float(((unsigned)v) << 16);
}
__device__ __forceinline__ float bflo(unsigned u) { return __uint_as_float(u << 16); }
__device__ __forceinline__ float bfhi(unsigned u) { return __uint_as_float(u & 0xffff0000u); }

__device__ void mul3(const double* a, const double* b, double* o) {
    for (int i = 0; i < 3; i++)
        for (int j = 0; j < 3; j++) {
            double s = 0.0;
            for (int k = 0; k < 3; k++) s += a[i*3+k]*b[k*3+j];
            o[i*3+j] = s;
        }
}

// ---- kernel 0: poses (double math), minmax reduction (no atomics), bf16 weights ----
__global__ void k_init(float* ws, const float* __restrict__ W1,
                       const float* __restrict__ W2, const float* __restrict__ b2,
                       const float* __restrict__ noise) {
    __shared__ float redmn[4], redmx[4];
    int t = threadIdx.x;
    if (t < 32) {
        double y = 1.0 - (t/31.0)*2.0;
        double rr = sqrt(fmax(1.0 - y*y, 0.0));
        double golden = M_PI*(sqrt(5.0) - 1.0);
        double th = golden*(double)t;
        double x = cos(th)*rr, z = sin(th)*rr;
        double phi   = atan2(z, sqrt(x*x + y*y));   // radians treated as degrees (faithful)
        double theta = atan2(y, x);
        double p  = phi/180.0*M_PI;
        double tt = theta/180.0*M_PI;
        double e  = 90.0/180.0*M_PI;
        double cp = cos(p), sp = sin(p), ct = cos(tt), st = sin(tt);
        double ce = cos(e), se = sin(e);
        double Ph[9] = {1,0,0,  0,cp,-sp,  0,sp,cp};
        double Th[9] = {ct,0,-st,  0,1,0,  st,0,ct};
        double Et[9] = {ce,se,0,  -se,ce,0,  0,0,1};
        double M3[9] = {-1,0,0,  0,0,1,  0,1,0};
        double A[9], Bm[9], R[9];
        mul3(Th, Ph, A);
        mul3(Et, A, Bm);
        mul3(M3, Bm, R);
        double radius = -1.307;
        double tv0 = radius*R[2], tv1 = radius*R[5], tv2 = radius*R[8];
        double Rf[9] = {-R[0],R[1],R[2], -R[3],R[4],R[5], -R[6],R[7],R[8]};
        float* P = ws + OFF_POSES + t*12;
        for (int j = 0; j < 3; j++) {
            double r0 = Rf[0*3+j], r1 = Rf[1*3+j], r2 = Rf[2*3+j];
            P[j*4+0] = (float)r0;
            P[j*4+1] = (float)r1;
            P[j*4+2] = (float)r2;
            P[j*4+3] = (float)(-(r0*tv0 + r1*tv1 + r2*tv2));
        }
    }
    unsigned short* w1e = (unsigned short*)(ws + OFF_W1E);
    for (int idx = t; idx < 64*256; idx += 256) {
        int n = idx >> 8, k = idx & 255;
        int p = k >> 3, f = k & 7;
        float v = 0.f;
        if (f < 3)      v = W1[(3*p+f)*64 + n];
        else if (f < 5) v = W1[(96 + 2*p + (f-3))*64 + n];
        w1e[idx] = bf16rne(v);
    }
    unsigned short* w2e = (unsigned short*)(ws + OFF_W2E);
    for (int idx = t; idx < 48*64; idx += 256) {
        int n = idx >> 6, k = idx & 63;
        float v = (n < 33) ? W2[k*33 + n] : 0.f;
        w2e[idx] = bf16rne(v);
    }
    for (int idx = t; idx < 48; idx += 256)
        ws[OFF_B2E + idx] = (idx < 33) ? b2[idx] : 0.f;

    // minmax over noise col 0 / col 47 (one block, no atomics)
    float mn = 1e30f, mx = -1e30f;
    for (int r = t; r < NRAYS; r += 256) {
        float n0  = noise[(size_t)r*48];
        float n47 = noise[(size_t)r*48 + 47];
        mn = fminf(mn, 0.5f + n0*DELTA_);
        mx = fmaxf(mx, 0.5f + 47.f*DELTA_ + n47*DELTA_);
    }
    for (int off = 32; off > 0; off >>= 1) {
        mn = fminf(mn, __shfl_down(mn, off));
        mx = fmaxf(mx, __shfl_down(mx, off));
    }
    if ((t & 63) == 0) { redmn[t >> 6] = mn; redmx[t >> 6] = mx; }
    __syncthreads();
    if (t == 0) {
        ws[OFF_MINMAX]     = fminf(fminf(redmn[0], redmn[1]), fminf(redmn[2], redmn[3]));
        ws[OFF_MINMAX + 1] = fmaxf(fmaxf(redmx[0], redmx[1]), fmaxf(redmx[2], redmx[3]));
    }
}

// ---- kernel 1: repack planes to guard-padded bf16 single texels (8B) ----
__global__ __launch_bounds__(256) void k_repack(const float* __restrict__ planes, uint2* __restrict__ st) {
    int idx = blockIdx.x*256 + threadIdx.x;
    if (idx >= ST_TOTAL) return;
    int bp = idx / ST_ENT;
    int rem = idx - bp*ST_ENT;
    int j = rem / 66, i = rem - j*66;
    unsigned ux = 0, uy = 0;
    if (j >= 1 && j <= 64 && i >= 1 && i <= 64) {
        int b = bp >> 5, p = bp & 31;
        const float* src = planes + (((size_t)b*96 + 3*p)*64 + (j-1))*64 + (i-1);
        ux = bf16pk(src[0], src[4096]);
        uy = (unsigned)bf16rne(src[8192]);
    }
    st[idx] = make_uint2(ux, uy);
}

// ---- kernel 1b: point prepass — position+depth once per point ----
__global__ __launch_bounds__(256) void k_pts(
    const float* __restrict__ noise, const float* __restrict__ ro,
    const float* __restrict__ rd, const float* __restrict__ dfin,
    float* __restrict__ dcout, float4* __restrict__ pts, int coarse)
{
    int pt = blockIdx.x*256 + threadIdx.x;
    if (pt >= NPTS) return;
    int ray = pt / S_;
    float depth;
    if (coarse) {
        int j = pt - ray*S_;
        depth = 0.5f + (float)j*DELTA_ + noise[pt]*DELTA_;
        dcout[pt] = depth;
    } else depth = dfin[pt];
    float px = fmaf(depth, rd[ray*3+0], ro[ray*3+0]);
    float py = fmaf(depth, rd[ray*3+1], ro[ray*3+1]);
    float pz = fmaf(depth, rd[ray*3+2], ro[ray*3+2]);
    pts[pt] = make_float4(px, py, pz, depth);
}

// ---- kernel 2a: LDS-staged gather, 512 threads (32 waves/CU at 4 blocks) ----
__global__ __launch_bounds__(512) void k_gather(
    const uint2* __restrict__ st, const float4* __restrict__ pts,
    const float* __restrict__ poses,
    unsigned short* __restrict__ feats, unsigned* __restrict__ gxy,
    int base_pt, int chunk_pts)
{
    __shared__ uint2 tex[ST_ENT];       // 34848 B
    int tid = threadIdx.x;
    int p  = blockIdx.x & 31;           // plane
    int pr = blockIdx.x >> 5;           // point-range index within chunk
    int r0 = pr*PTS_BLK;
    int b = (base_pt + r0 >= NPTS/2) ? 1 : 0;   // PTS_BLK divides NPTS/2
    const uint2* src = st + (size_t)(b*32 + p)*ST_ENT;
    for (int i = tid; i < ST_ENT; i += 512) tex[i] = src[i];
    const float* P = poses + p*12;
    float P0 = P[0], P1 = P[1], P2 = P[2],  P3 = P[3];
    float P4 = P[4], P5 = P[5], P6 = P[6],  P7 = P[7];
    float P8 = P[8], P9 = P[9], P10 = P[10], P11 = P[11];
    __syncthreads();

    for (int it = 0; it < PTS_BLK/512; it++) {
        int ptl = r0 + it*512 + tid;
        float4 pv = pts[base_pt + ptl];
        float px = pv.x, py = pv.y, pz = pv.z;
        float c0 = fmaf(P0,px, fmaf(P1,py, fmaf(P2,pz, P3)));
        float c1 = fmaf(P4,px, fmaf(P5,py, fmaf(P6,pz, P7)));
        float c2 = fmaf(P8,px, fmaf(P9,py, fmaf(P10,pz, P11)));
        float rz = __builtin_amdgcn_rcpf(c2);
        float gx = fminf(fmaxf((1.0254f*c0 + 0.5f*c2)*rz, 0.f), 1.f)*2.f - 1.f;
        float gy = fminf(fmaxf((1.0254f*c1 + 0.5f*c2)*rz, 0.f), 1.f)*2.f - 1.f;
        float ixp = ((gx + 1.f)*64.f - 1.f)*0.5f + 1.f;
        float iyp = ((gy + 1.f)*64.f - 1.f)*0.5f + 1.f;
        float xf = floorf(ixp), yf = floorf(iyp);
        float wx = ixp - xf, wy = iyp - yf;
        int x0p = (int)xf, y0p = (int)yf;     // [0,64]
        const uint2* e = tex + y0p*66 + x0p;
        uint2 e00 = e[0], e01 = e[1], e10 = e[66], e11 = e[67];
        float wy0 = 1.f - wy, wy1 = wy;
        float w0x = 1.f - wx, w1x = wx;
        float tl0 = fmaf(wy0, bflo(e00.x), wy1*bflo(e10.x));
        float tl1 = fmaf(wy0, bfhi(e00.x), wy1*bfhi(e10.x));
        float tl2 = fmaf(wy0, bflo(e00.y), wy1*bflo(e10.y));
        float tr0 = fmaf(wy0, bflo(e01.x), wy1*bflo(e11.x));
        float tr1 = fmaf(wy0, bfhi(e01.x), wy1*bfhi(e11.x));
        float tr2 = fmaf(wy0, bflo(e01.y), wy1*bflo(e11.y));
        float f0 = fmaf(w0x, tl0, w1x*tr0);
        float f1 = fmaf(w0x, tl1, w1x*tr1);
        float f2 = fmaf(w0x, tl2, w1x*tr2);
        size_t slot = (size_t)p*chunk_pts + ptl;
        uint2 av;
        av.x = bf16pk(f0, f1);
        av.y = (unsigned)bf16rne(f2);
        *(uint2*)(feats + slot*4) = av;
        gxy[slot] = bf16pk(gx, gy);
    }
}

// ---- kernel 2b: MFMA MLP — pure GEMM, fully-unrolled K-loop ----
__global__ __launch_bounds__(256) void k_mlp(
    const unsigned short* __restrict__ feats, const unsigned* __restrict__ gxy,
    const float* __restrict__ b1, const unsigned short* __restrict__ w1e,
    const unsigned short* __restrict__ w2e, const float* __restrict__ b2e,
    unsigned short* __restrict__ colors, float* __restrict__ dens,
    int base_pt, int chunk_pts)
{
    __shared__ __align__(16) unsigned short smem[4][4608];
    int tid = threadIdx.x;
    int wv = tid >> 6, lane = tid & 63;
    int n = lane & 15, q = lane >> 4;
    int wlocal = blockIdx.x*256 + wv*64;

    f32x4 acc[4][4];
#pragma unroll
    for (int t = 0; t < 4; t++)
#pragma unroll
        for (int nt = 0; nt < 4; nt++) {
            float bv = b1[nt*16 + n];
            acc[t][nt] = (f32x4){bv, bv, bv, bv};
        }

#pragma unroll
    for (int s = 0; s < 8; s++) {
        short8 bf[4];
#pragma unroll
        for (int nt = 0; nt < 4; nt++)
            bf[nt] = *(const short8*)(w1e + (nt*16 + n)*256 + s*32 + q*8);
        int plane = s*4 + q;
#pragma unroll
        for (int t = 0; t < 4; t++) {
            size_t slot = (size_t)plane*chunk_pts + wlocal + t*16 + n;
            uint2 fv = *(const uint2*)(feats + slot*4);
            unsigned g = gxy[slot];
            union { short8 s8; uint4 u; } av;
            av.u.x = fv.x;                                      // f0,f1
            av.u.y = (fv.y & 0xffffu) | (g << 16);              // f2,gx
            av.u.z = g >> 16;                                   // gy,0
            av.u.w = 0u;
#pragma unroll
            for (int nt = 0; nt < 4; nt++)
                acc[t][nt] = __builtin_amdgcn_mfma_f32_16x16x32_bf16(av.s8, bf[nt], acc[t][nt], 0, 0, 0);
        }
    }

    unsigned short* ht = &smem[wv][0];
#pragma unroll
    for (int t = 0; t < 4; t++)
#pragma unroll
        for (int nt = 0; nt < 4; nt++)
#pragma unroll
            for (int r = 0; r < 4; r++) {
                float hv = softplus_f(acc[t][nt][r]);
                ht[(t*16 + q*4 + r)*72 + nt*16 + n] = bf16rne(hv);
            }
    short8 a2[4][2];
#pragma unroll
    for (int t = 0; t < 4; t++)
#pragma unroll
        for (int s2 = 0; s2 < 2; s2++)
            a2[t][s2] = *(const short8*)(ht + (t*16 + n)*72 + s2*32 + q*8);
    // no __syncthreads: aliasing is wave-local; DS pipe in-order per wave

    f32x4 acc2[4][3];
#pragma unroll
    for (int t = 0; t < 4; t++)
#pragma unroll
        for (int nt = 0; nt < 3; nt++) {
            float bv = b2e[nt*16 + n];
            acc2[t][nt] = (f32x4){bv, bv, bv, bv};
        }
    short8 b2f[3][2];
#pragma unroll
    for (int nt = 0; nt < 3; nt++)
#pragma unroll
        for (int s2 = 0; s2 < 2; s2++)
            b2f[nt][s2] = *(const short8*)(w2e + (nt*16 + n)*64 + s2*32 + q*8);
#pragma unroll
    for (int t = 0; t < 4; t++)
#pragma unroll
        for (int nt = 0; nt < 3; nt++)
#pragma unroll
            for (int s2 = 0; s2 < 2; s2++)
                acc2[t][nt] = __builtin_amdgcn_mfma_f32_16x16x32_bf16(a2[t][s2], b2f[nt][s2], acc2[t][nt], 0, 0, 0);

    float* ot = (float*)&smem[wv][0];
#pragma unroll
    for (int t = 0; t < 4; t++)
#pragma unroll
        for (int nt = 0; nt < 3; nt++) {
            int col = nt*16 + n;
#pragma unroll
            for (int r = 0; r < 4; r++) {
                float v = acc2[t][nt][r];
                int row = t*16 + q*4 + r;
                if (col == 0) ot[row*34 + 32] = v;
                else if (col <= 32) {
                    float sg = sigmoid_f(v);
                    ot[row*34 + (col-1)] = fmaf(sg, 1.002f, -0.001f);
                }
            }
        }
    unsigned* cgu = (unsigned*)(colors + (size_t)(base_pt + wlocal)*32);
    for (int i = 0; i < 16; i++) {
        int ui = i*64 + lane;
        int pt = ui >> 4, ch = (ui & 15)*2;
        cgu[ui] = bf16pk(ot[pt*34 + ch], ot[pt*34 + ch + 1]);
    }
    dens[base_pt + wlocal + lane] = ot[lane*34 + 32];
}

// ---- kernel 3: coarse march + pdf + importance samples (wave per ray) ----
__global__ __launch_bounds__(256) void k_imp(const float* __restrict__ u, float* ws) {
    __shared__ float zl[4][48];
    __shared__ float cdfl[4][46];
    int tid = threadIdx.x;
    int wv = tid >> 6, lane = tid & 63;
    int r = blockIdx.x*4 + wv;
    const float* z   = ws + OFF_DC + (size_t)r*48;
    const float* den = ws + OFF_SC + (size_t)r*48;
    float zv = 0.f, dv = 0.f;
    if (lane < 48) { zv = z[lane]; dv = den[lane]; zl[wv][lane] = zv; }
    float zn  = __shfl_down(zv, 1);
    float dnn = __shfl_down(dv, 1);
    float alpha = 0.f, f = 1.f;
    if (lane < 47) {
        float sp = softplus_f(0.5f*(dv + dnn) - 1.f);
        alpha = 1.f - __expf(-sp*(zn - zv));
        f = 1.f - alpha + 1e-10f;
    }
    float v = f;
    for (int off = 1; off < 64; off <<= 1) { float o = __shfl_up(v, off); if (lane >= off) v *= o; }
    float T = __shfl_up(v, 1); if (lane == 0) T = 1.f;
    float w = alpha*T;
    float wn1 = __shfl_down(w, 1), wn2 = __shfl_down(w, 2);
    float pw = 0.f;
    if (lane < 45) pw = 0.5f*(fmaxf(w, wn1) + fmaxf(wn1, wn2)) + 0.01f + 1e-5f;
    float s = pw;
    for (int off = 1; off < 64; off <<= 1) { float o = __shfl_up(s, off); if (lane >= off) s += o; }
    float csum = __shfl(s, 63);
    if (lane < 45) cdfl[wv][lane+1] = s/csum;
    if (lane == 63) cdfl[wv][0] = 0.f;
    __syncthreads();
    if (lane < 48) {
        float uu = u[(size_t)r*48 + lane];
        int lo = 0, hi = 46;
        while (lo < hi) { int mid = (lo+hi)>>1; if (uu >= cdfl[wv][mid]) lo = mid+1; else hi = mid; }
        int below = max(lo-1, 0), above = min(lo, 45);
        float cb = cdfl[wv][below], ca = cdfl[wv][above];
        float zb = zl[wv][below],   za = zl[wv][above];
        float dn2 = ca - cb; if (dn2 < 1e-5f) dn2 = 1.f;
        ws[OFF_DF + (size_t)r*48 + lane] = zb + (uu - cb)/dn2*(za - zb);
    }
}

// ---- kernel 5: fused sort + march + color accumulation (wave per ray) ----
__global__ __launch_bounds__(256) void k_final(float* __restrict__ out, const float* __restrict__ ws,
                                               const unsigned short* __restrict__ cC,
                                               const unsigned short* __restrict__ cF)
{
    __shared__ float kd[4][96];
    __shared__ float kden[4][96];
    __shared__ float sdl[4][96];
    __shared__ float sdenl[4][96];
    __shared__ int   sidxl[4][96];
    __shared__ float warr[4][96];
    __shared__ float earr[4][96];
    int tid = threadIdx.x;
    int wv = tid >> 6, lane = tid & 63;
    int r = blockIdx.x*4 + wv;
    const float* dc = ws + OFF_DC + (size_t)r*48;
    const float* df = ws + OFF_DF + (size_t)r*48;
    const float* sc = ws + OFF_SC + (size_t)r*48;
    const float* sf = ws + OFF_SF + (size_t)r*48;
    for (int i = lane; i < 96; i += 64) {
        float d, dn;
        if (i < 48) { d = dc[i]; dn = sc[i]; }
        else        { d = df[i-48]; dn = sf[i-48]; }
        kd[wv][i] = d; kden[wv][i] = dn;
    }
    __syncthreads();
    for (int i = lane; i < 96; i += 64) {
        float d = kd[wv][i];
        int rank = 0;
        for (int j = 0; j < 96; j++) {
            float dj = kd[wv][j];
            rank += (int)((dj < d) | ((dj == d) & (j < i)));
        }
        sdl[wv][rank] = d; sdenl[wv][rank] = kden[wv][i]; sidxl[wv][rank] = i;
    }
    __syncthreads();
    int i2 = 2*lane;
    float a0=0.f, f0=1.f, a1=0.f, f1=1.f, d0=0.f, d1=0.f, d2=0.f;
    if (i2 < 95) {
        d0 = sdl[wv][i2]; d1 = sdl[wv][i2+1];
        float sp = softplus_f(0.5f*(sdenl[wv][i2] + sdenl[wv][i2+1]) - 1.f);
        a0 = 1.f - __expf(-sp*(d1 - d0)); f0 = 1.f - a0 + 1e-10f;
    }
    if (i2+1 < 95) {
        d2 = sdl[wv][i2+2];
        float sp = softplus_f(0.5f*(sdenl[wv][i2+1] + sdenl[wv][i2+2]) - 1.f);
        a1 = 1.f - __expf(-sp*(d2 - d1)); f1 = 1.f - a1 + 1e-10f;
    }
    float p = f0*f1, v = p;
    for (int off = 1; off < 64; off <<= 1) { float o = __shfl_up(v, off); if (lane >= off) v *= o; }
    float excl = __shfl_up(v, 1); if (lane == 0) excl = 1.f;
    float w0 = a0*excl, w1 = a1*excl*f0;
    if (i2   < 96) warr[wv][i2]   = w0;
    if (i2+1 < 96) warr[wv][i2+1] = w1;
    float wsm = w0 + w1;
    float dsm = w0*0.5f*(d0+d1) + w1*0.5f*(d1+d2);
    for (int off = 32; off; off >>= 1) { wsm += __shfl_xor(wsm, off); dsm += __shfl_xor(dsm, off); }
    __syncthreads();
    for (int i = lane; i < 96; i += 64) {
        float wp = (i > 0)  ? warr[wv][i-1] : 0.f;
        float wc = (i < 95) ? warr[wv][i]   : 0.f;
        earr[wv][sidxl[wv][i]] = 0.5f*(wp + wc);
    }
    __syncthreads();
    int ch = lane & 31, half = lane >> 5;
    const unsigned short* cbase = (half ? cF : cC) + ((size_t)r*48)*32 + ch;
    const float* eb = &earr[wv][half*48];
    float a = 0.f;
    for (int jj = 0; jj < 48; jj++)
        a = fmaf(eb[jj], bf2f(cbase[(size_t)jj*32]), a);
    a += __shfl_xor(a, 32);
    if (lane < 32) out[(size_t)r*34 + lane] = 2.f*a - 1.f;
    if (lane == 0) {
        float gmn = ws[OFF_MINMAX];
        float gmx = ws[OFF_MINMAX + 1];
        float depth = dsm/wsm;
        if (depth != depth) depth = __builtin_inff();
        depth = fminf(fmaxf(depth, gmn), gmx);
        out[(size_t)r*34 + 32] = depth;
        out[(size_t)r*34 + 33] = wsm;
    }
}

extern "C" void kernel_launch(void* const* d_in, const int* in_sizes, int n_in,
                              void* d_out, int out_size, void* d_ws, size_t ws_size,
                              hipStream_t stream) {
    const float* planes = (const float*)d_in[0];
    const float* ro     = (const float*)d_in[1];
    const float* rd     = (const float*)d_in[2];
    const float* noise  = (const float*)d_in[3];
    const float* u      = (const float*)d_in[4];
    const float* W1     = (const float*)d_in[5];
    const float* b1     = (const float*)d_in[6];
    const float* W2     = (const float*)d_in[7];
    const float* b2     = (const float*)d_in[8];
    float* ws  = (float*)d_ws;
    float* out = (float*)d_out;
    const unsigned short* w1e = (const unsigned short*)(ws + OFF_W1E);
    const unsigned short* w2e = (const unsigned short*)(ws + OFF_W2E);
    uint2* st = (uint2*)(ws + OFF_ST);
    float4* pts = (float4*)(ws + OFF_PTS);
    unsigned short* cC = (unsigned short*)(ws + OFF_CC);
    unsigned short* cF = (unsigned short*)(ws + OFF_CF);

    // chunk: feats = chunk*64 floats, gxy = chunk*32 floats
    long cap = (long)(ws_size/sizeof(float)) - OFF_FEATS;
    int chunk = NPTS;
    while ((long)chunk*96 > cap && chunk > PTS_BLK) chunk >>= 1;
    int nch = NPTS/chunk;
    unsigned short* feats = (unsigned short*)(ws + OFF_FEATS);
    unsigned* gxy = (unsigned*)(ws + OFF_FEATS + (size_t)chunk*64);

    hipLaunchKernelGGL(k_init,   dim3(1),    dim3(256), 0, stream, ws, W1, W2, b2, noise);
    hipLaunchKernelGGL(k_repack, dim3((ST_TOTAL + 255)/256), dim3(256), 0, stream, planes, st);
    hipLaunchKernelGGL(k_pts,    dim3(NPTS/256), dim3(256), 0, stream,
                       noise, ro, rd, (const float*)nullptr, ws + OFF_DC, pts, 1);
    for (int c = 0; c < nch; c++) {
        hipLaunchKernelGGL(k_gather, dim3((chunk/PTS_BLK)*32), dim3(512), 0, stream,
                           st, pts, ws + OFF_POSES, feats, gxy, c*chunk, chunk);
        hipLaunchKernelGGL(k_mlp,    dim3(chunk/256), dim3(256), 0, stream,
                           feats, gxy, b1, w1e, w2e, ws + OFF_B2E, cC, ws + OFF_SC, c*chunk, chunk);
    }
    hipLaunchKernelGGL(k_imp, dim3(NRAYS/4), dim3(256), 0, stream, u, ws);
    hipLaunchKernelGGL(k_pts, dim3(NPTS/256), dim3(256), 0, stream,
                       noise, ro, rd, ws + OFF_DF, ws + OFF_DC, pts, 0);
    for (int c = 0; c < nch; c++) {
        hipLaunchKernelGGL(k_gather, dim3((chunk/PTS_BLK)*32), dim3(512), 0, stream,
                           st, pts, ws + OFF_POSES, feats, gxy, c*chunk, chunk);
        hipLaunchKernelGGL(k_mlp,    dim3(chunk/256), dim3(256), 0, stream,
                           feats, gxy, b1, w1e, w2e, ws + OFF_B2E, cF, ws + OFF_SF, c*chunk, chunk);
    }
    hipLaunchKernelGGL(k_final, dim3(NRAYS/4), dim3(256), 0, stream, out, ws, cC, cF);
}